// Round 1
// baseline (9659.778 us; speedup 1.0000x reference)
//
#include <hip/hip_runtime.h>
#include <math.h>

#define N_NODES 20000
#define N_EDGES 320000

// ---- ordered-uint encoding for float atomicMax ----
__device__ __forceinline__ unsigned int enc_f(float f) {
    unsigned int u = __float_as_uint(f);
    return (u & 0x80000000u) ? ~u : (u | 0x80000000u);
}
__device__ __forceinline__ float dec_f(unsigned int e) {
    return (e & 0x80000000u) ? __uint_as_float(e & 0x7fffffffu) : __uint_as_float(~e);
}

// ---- in_proj: h0[N,32] = x[N,18] @ W[18,32] + b ----
__global__ void k_inproj(const float* __restrict__ x, const float* __restrict__ W,
                         const float* __restrict__ b, float* __restrict__ h0) {
    int t = blockIdx.x * blockDim.x + threadIdx.x;
    if (t >= N_NODES * 32) return;
    int n = t >> 5, p = t & 31;
    float acc = b[p];
    const float* xr = x + n * 18;
#pragma unroll
    for (int k = 0; k < 18; k++) acc = fmaf(xr[k], W[k * 32 + p], acc);
    h0[t] = acc;
}

// ---- dual GEMM K=32: xl = h0@Wl, xr = h0@Wr (one node per block) ----
__global__ void k_dual32(const float* __restrict__ h0, const float* __restrict__ Wl,
                         const float* __restrict__ Wr, float* __restrict__ xl,
                         float* __restrict__ xr) {
    __shared__ float hs[32];
    int n = blockIdx.x;
    int j = threadIdx.x;
    if (j < 32) hs[j] = h0[n * 32 + j];
    __syncthreads();
    float al = 0.f, ar = 0.f;
#pragma unroll
    for (int k = 0; k < 32; k++) {
        float hv = hs[k];
        al = fmaf(hv, Wl[k * 256 + j], al);
        ar = fmaf(hv, Wr[k * 256 + j], ar);
    }
    xl[(size_t)n * 256 + j] = al;
    xr[(size_t)n * 256 + j] = ar;
}

// ---- generic fp32 GEMM: C[M,N] = A[M,K] @ B[K,N] (+ bias), 64x64 tiles ----
__global__ __launch_bounds__(256) void k_gemm(const float* __restrict__ A,
                                              const float* __restrict__ B,
                                              float* __restrict__ C,
                                              const float* __restrict__ bias,
                                              int M, int N, int K) {
    __shared__ float As[16][65];  // [k][m]
    __shared__ float Bs[16][65];  // [k][n]
    int tid = threadIdx.x;
    int tx = tid & 15, ty = tid >> 4;
    int row0 = blockIdx.x * 64, col0 = blockIdx.y * 64;
    float acc[4][4] = {};
    int ar = tid >> 2, ak = (tid & 3) * 4;   // A loader: row ar, 4 k's at ak
    int bk = tid >> 4, bc = (tid & 15) * 4;  // B loader: k-row bk, 4 cols at bc
    for (int k0 = 0; k0 < K; k0 += 16) {
        float4 av = make_float4(0.f, 0.f, 0.f, 0.f);
        if (row0 + ar < M) av = *(const float4*)(A + (size_t)(row0 + ar) * K + k0 + ak);
        As[ak + 0][ar] = av.x; As[ak + 1][ar] = av.y;
        As[ak + 2][ar] = av.z; As[ak + 3][ar] = av.w;
        float4 bv = make_float4(0.f, 0.f, 0.f, 0.f);
        if (col0 + bc < N) bv = *(const float4*)(B + (size_t)(k0 + bk) * N + col0 + bc);
        Bs[bk][bc + 0] = bv.x; Bs[bk][bc + 1] = bv.y;
        Bs[bk][bc + 2] = bv.z; Bs[bk][bc + 3] = bv.w;
        __syncthreads();
#pragma unroll
        for (int kk = 0; kk < 16; kk++) {
            float a0 = As[kk][ty * 4 + 0], a1 = As[kk][ty * 4 + 1];
            float a2 = As[kk][ty * 4 + 2], a3 = As[kk][ty * 4 + 3];
            float b0 = Bs[kk][tx * 4 + 0], b1 = Bs[kk][tx * 4 + 1];
            float b2 = Bs[kk][tx * 4 + 2], b3 = Bs[kk][tx * 4 + 3];
            acc[0][0] = fmaf(a0, b0, acc[0][0]); acc[0][1] = fmaf(a0, b1, acc[0][1]);
            acc[0][2] = fmaf(a0, b2, acc[0][2]); acc[0][3] = fmaf(a0, b3, acc[0][3]);
            acc[1][0] = fmaf(a1, b0, acc[1][0]); acc[1][1] = fmaf(a1, b1, acc[1][1]);
            acc[1][2] = fmaf(a1, b2, acc[1][2]); acc[1][3] = fmaf(a1, b3, acc[1][3]);
            acc[2][0] = fmaf(a2, b0, acc[2][0]); acc[2][1] = fmaf(a2, b1, acc[2][1]);
            acc[2][2] = fmaf(a2, b2, acc[2][2]); acc[2][3] = fmaf(a2, b3, acc[2][3]);
            acc[3][0] = fmaf(a3, b0, acc[3][0]); acc[3][1] = fmaf(a3, b1, acc[3][1]);
            acc[3][2] = fmaf(a3, b2, acc[3][2]); acc[3][3] = fmaf(a3, b3, acc[3][3]);
        }
        __syncthreads();
    }
#pragma unroll
    for (int i = 0; i < 4; i++) {
        int r = row0 + ty * 4 + i;
        if (r >= M) continue;
#pragma unroll
        for (int j = 0; j < 4; j++) {
            int c = col0 + tx * 4 + j;
            if (c >= N) continue;
            float v = acc[i][j];
            if (bias) v += bias[c];
            C[(size_t)r * N + c] = v;
        }
    }
}

// ---- edge scores + segment max (thread per (edge,head)) ----
__global__ void k_edge_score(const float* __restrict__ xl, const float* __restrict__ xr,
                             const float* __restrict__ ea, const float* __restrict__ We,
                             const float* __restrict__ att, const int* __restrict__ src,
                             const int* __restrict__ dst, float* __restrict__ score,
                             unsigned int* __restrict__ mbuf) {
    int t = blockIdx.x * blockDim.x + threadIdx.x;
    if (t >= N_EDGES * 8) return;
    int e = t >> 3, h = t & 7;
    int s = src[e], d = dst[e];
    float a = ea[e];
    const float4* l4 = (const float4*)(xl + (size_t)s * 256 + h * 32);
    const float4* r4 = (const float4*)(xr + (size_t)d * 256 + h * 32);
    const float4* w4 = (const float4*)(We + h * 32);
    const float4* t4 = (const float4*)(att + h * 32);
    float sc = 0.f;
#pragma unroll
    for (int i = 0; i < 8; i++) {
        float4 lv = l4[i], rv = r4[i], wv = w4[i], av = t4[i];
        float f;
        f = lv.x + rv.x + a * wv.x; f = (f >= 0.f) ? f : 0.2f * f; sc = fmaf(f, av.x, sc);
        f = lv.y + rv.y + a * wv.y; f = (f >= 0.f) ? f : 0.2f * f; sc = fmaf(f, av.y, sc);
        f = lv.z + rv.z + a * wv.z; f = (f >= 0.f) ? f : 0.2f * f; sc = fmaf(f, av.z, sc);
        f = lv.w + rv.w + a * wv.w; f = (f >= 0.f) ? f : 0.2f * f; sc = fmaf(f, av.w, sc);
    }
    score[t] = sc;
    atomicMax(mbuf + (size_t)d * 8 + h, enc_f(sc));
}

// ---- exp(score - max) + segment sum ----
__global__ void k_edge_exp(const int* __restrict__ dst, const unsigned int* __restrict__ mbuf,
                           float* __restrict__ score, float* __restrict__ sbuf) {
    int t = blockIdx.x * blockDim.x + threadIdx.x;
    if (t >= N_EDGES * 8) return;
    int e = t >> 3, h = t & 7;
    int d = dst[e];
    float ex = expf(score[t] - dec_f(mbuf[(size_t)d * 8 + h]));
    score[t] = ex;
    atomicAdd(sbuf + (size_t)d * 8 + h, ex);
}

// ---- weighted scatter aggregate: out[dst] += alpha * xl[src] ----
__global__ void k_edge_agg(const int* __restrict__ src, const int* __restrict__ dst,
                           const float* __restrict__ ex, const float* __restrict__ sbuf,
                           const float* __restrict__ xl, float* __restrict__ out) {
    int t = blockIdx.x * blockDim.x + threadIdx.x;
    if (t >= N_EDGES * 8) return;
    int e = t >> 3, h = t & 7;
    int s = src[e], d = dst[e];
    float alpha = ex[t] / (sbuf[(size_t)d * 8 + h] + 1e-16f);
    const float4* l4 = (const float4*)(xl + (size_t)s * 256 + h * 32);
    float* op = out + (size_t)d * 256 + h * 32;
#pragma unroll
    for (int i = 0; i < 8; i++) {
        float4 v = l4[i];
        atomicAdd(op + 4 * i + 0, alpha * v.x);
        atomicAdd(op + 4 * i + 1, alpha * v.y);
        atomicAdd(op + 4 * i + 2, alpha * v.z);
        atomicAdd(op + 4 * i + 3, alpha * v.w);
    }
}

// ---- LayerNorm over 256 dims, one wave per row: out = LN(in [+res] [+vbias]) * g + b ----
__global__ void k_ln(const float* __restrict__ in, const float* __restrict__ res,
                     const float* __restrict__ vbias, const float* __restrict__ g,
                     const float* __restrict__ b, float* __restrict__ out, int rows) {
    int gt = blockIdx.x * blockDim.x + threadIdx.x;
    int wid = gt >> 6, lane = threadIdx.x & 63;
    if (wid >= rows) return;
    float4 v = ((const float4*)(in + (size_t)wid * 256))[lane];
    if (res) {
        float4 r = ((const float4*)(res + (size_t)wid * 256))[lane];
        v.x += r.x; v.y += r.y; v.z += r.z; v.w += r.w;
    }
    if (vbias) {
        float4 r = ((const float4*)vbias)[lane];
        v.x += r.x; v.y += r.y; v.z += r.z; v.w += r.w;
    }
    float sum = v.x + v.y + v.z + v.w;
#pragma unroll
    for (int o = 32; o > 0; o >>= 1) sum += __shfl_xor(sum, o, 64);
    float mean = sum * (1.0f / 256.0f);
    float dx = v.x - mean, dy = v.y - mean, dz = v.z - mean, dw = v.w - mean;
    float sq = dx * dx + dy * dy + dz * dz + dw * dw;
#pragma unroll
    for (int o = 32; o > 0; o >>= 1) sq += __shfl_xor(sq, o, 64);
    float inv = 1.0f / sqrtf(sq * (1.0f / 256.0f) + 1e-5f);
    float4 gg = ((const float4*)g)[lane];
    float4 bb = ((const float4*)b)[lane];
    float4 o4 = make_float4(dx * inv * gg.x + bb.x, dy * inv * gg.y + bb.y,
                            dz * inv * gg.z + bb.z, dw * inv * gg.w + bb.w);
    ((float4*)(out + (size_t)wid * 256))[lane] = o4;
}

extern "C" void kernel_launch(void* const* d_in, const int* in_sizes, int n_in,
                              void* d_out, int out_size, void* d_ws, size_t ws_size,
                              hipStream_t stream) {
    const float* x_gnn = (const float*)d_in[0];
    const int* ei = (const int*)d_in[1];
    const int* src = ei;
    const int* dst = ei + N_EDGES;
    const float* ea   = (const float*)d_in[2];
    const float* W_in = (const float*)d_in[3];
    const float* b_in = (const float*)d_in[4];
    const float* Wl1  = (const float*)d_in[5];
    const float* Wr1  = (const float*)d_in[6];
    const float* We1  = (const float*)d_in[7];
    const float* att1 = (const float*)d_in[8];
    const float* bg1  = (const float*)d_in[9];
    const float* ln1_g = (const float*)d_in[10];
    const float* ln1_b = (const float*)d_in[11];
    const float* W_down = (const float*)d_in[12];
    const float* lnd_g = (const float*)d_in[13];
    const float* lnd_b = (const float*)d_in[14];
    const float* Wl2  = (const float*)d_in[15];
    const float* Wr2  = (const float*)d_in[16];
    const float* We2  = (const float*)d_in[17];
    const float* att2 = (const float*)d_in[18];
    const float* bg2  = (const float*)d_in[19];
    const float* ln2_g = (const float*)d_in[20];
    const float* ln2_b = (const float*)d_in[21];
    const float* W_up = (const float*)d_in[22];
    const float* lnu_g = (const float*)d_in[23];
    const float* lnu_b = (const float*)d_in[24];
    const float* W_cls = (const float*)d_in[25];
    const float* b_cls = (const float*)d_in[26];

    // workspace layout (floats)
    float* ws = (float*)d_ws;
    float* B_h0 = ws;                                 // 640,000
    float* B_A  = B_h0 + 640000;                      // 5,120,000 (xl1 / xl2 / z2)
    float* B_B  = B_A + 5120000;                      // 5,120,000 (xr1 / xr2 / h2)
    float* B_S  = B_B + 5120000;                      // 2,560,000 (score / ex)
    unsigned int* B_m = (unsigned int*)(B_S + 2560000); // 160,000
    float* B_s  = (float*)(B_m + 160000);             // 160,000
    float* B_C  = B_s + 160000;                       // 5,120,000 (agg1 / zpre / agg2)
    float* B_h1 = B_C + 5120000;                      // 5,120,000
    float* B_z  = B_h1 + 5120000;                     // 5,120,000
    // total: 29,120,000 floats = 116.5 MB

    float* out_logits = (float*)d_out;
    float* out_h = out_logits + (size_t)N_NODES * 1000;

    int eth = N_EDGES * 8;
    int eblk = (eth + 255) / 256;
    int lnblk = (N_NODES * 64 + 255) / 256;
    dim3 gg((N_NODES + 63) / 64, (256 + 63) / 64);
    dim3 gc((N_NODES + 63) / 64, (1000 + 63) / 64);

    // 1. h0 = x @ W_in + b_in
    k_inproj<<<(N_NODES * 32 + 255) / 256, 256, 0, stream>>>(x_gnn, W_in, b_in, B_h0);
    // 2. xl1 = h0@Wl1, xr1 = h0@Wr1
    k_dual32<<<N_NODES, 256, 0, stream>>>(B_h0, Wl1, Wr1, B_A, B_B);
    // 3. GAT1
    hipMemsetAsync(B_m, 0, (size_t)160000 * 4, stream);
    hipMemsetAsync(B_s, 0, (size_t)160000 * 4, stream);
    hipMemsetAsync(B_C, 0, (size_t)5120000 * 4, stream);
    k_edge_score<<<eblk, 256, 0, stream>>>(B_A, B_B, ea, We1, att1, src, dst, B_S, B_m);
    k_edge_exp<<<eblk, 256, 0, stream>>>(dst, B_m, B_S, B_s);
    k_edge_agg<<<eblk, 256, 0, stream>>>(src, dst, B_S, B_s, B_A, B_C);
    // 4. h1 = LN(agg1 + bg1)
    k_ln<<<lnblk, 256, 0, stream>>>(B_C, nullptr, bg1, ln1_g, ln1_b, B_h1, N_NODES);
    // 5. z = LN(h1 @ W_down)
    k_gemm<<<gg, 256, 0, stream>>>(B_h1, W_down, B_C, nullptr, N_NODES, 256, 256);
    k_ln<<<lnblk, 256, 0, stream>>>(B_C, nullptr, nullptr, lnd_g, lnd_b, B_z, N_NODES);
    // 6. GAT2
    k_gemm<<<gg, 256, 0, stream>>>(B_z, Wl2, B_A, nullptr, N_NODES, 256, 256);
    k_gemm<<<gg, 256, 0, stream>>>(B_z, Wr2, B_B, nullptr, N_NODES, 256, 256);
    hipMemsetAsync(B_m, 0, (size_t)160000 * 4, stream);
    hipMemsetAsync(B_s, 0, (size_t)160000 * 4, stream);
    hipMemsetAsync(B_C, 0, (size_t)5120000 * 4, stream);
    k_edge_score<<<eblk, 256, 0, stream>>>(B_A, B_B, ea, We2, att2, src, dst, B_S, B_m);
    k_edge_exp<<<eblk, 256, 0, stream>>>(dst, B_m, B_S, B_s);
    k_edge_agg<<<eblk, 256, 0, stream>>>(src, dst, B_S, B_s, B_A, B_C);
    // 7. z2 = LN(agg2 + bg2 + z) -> B_A
    k_ln<<<lnblk, 256, 0, stream>>>(B_C, B_z, bg2, ln2_g, ln2_b, B_A, N_NODES);
    // 8. h2 = z2 @ W_up -> B_B
    k_gemm<<<gg, 256, 0, stream>>>(B_A, W_up, B_B, nullptr, N_NODES, 256, 256);
    // 9. h = LN(h1 + h2) -> out_h
    k_ln<<<lnblk, 256, 0, stream>>>(B_B, B_h1, nullptr, lnu_g, lnu_b, out_h, N_NODES);
    // 10. logits = h @ W_cls + b_cls
    k_gemm<<<gc, 256, 0, stream>>>(out_h, W_cls, out_logits, b_cls, N_NODES, 1000, 256);
}

// Round 2
// 1355.065 us; speedup vs baseline: 7.1286x; 7.1286x over previous
//
#include <hip/hip_runtime.h>
#include <math.h>

#define N_NODES 20000
#define N_EDGES 320000

// ---- ordered-uint encoding for float atomicMax ----
__device__ __forceinline__ unsigned int enc_f(float f) {
    unsigned int u = __float_as_uint(f);
    return (u & 0x80000000u) ? ~u : (u | 0x80000000u);
}
__device__ __forceinline__ float dec_f(unsigned int e) {
    return (e & 0x80000000u) ? __uint_as_float(e & 0x7fffffffu) : __uint_as_float(~e);
}

// ---- in_proj: h0[N,32] = x[N,18] @ W[18,32] + b ----
__global__ void k_inproj(const float* __restrict__ x, const float* __restrict__ W,
                         const float* __restrict__ b, float* __restrict__ h0) {
    int t = blockIdx.x * blockDim.x + threadIdx.x;
    if (t >= N_NODES * 32) return;
    int n = t >> 5, p = t & 31;
    float acc = b[p];
    const float* xr = x + n * 18;
#pragma unroll
    for (int k = 0; k < 18; k++) acc = fmaf(xr[k], W[k * 32 + p], acc);
    h0[t] = acc;
}

// ---- dual GEMM K=32: xl = h0@Wl, xr = h0@Wr (one node per block) ----
__global__ void k_dual32(const float* __restrict__ h0, const float* __restrict__ Wl,
                         const float* __restrict__ Wr, float* __restrict__ xl,
                         float* __restrict__ xr) {
    __shared__ float hs[32];
    int n = blockIdx.x;
    int j = threadIdx.x;
    if (j < 32) hs[j] = h0[n * 32 + j];
    __syncthreads();
    float al = 0.f, ar = 0.f;
#pragma unroll
    for (int k = 0; k < 32; k++) {
        float hv = hs[k];
        al = fmaf(hv, Wl[k * 256 + j], al);
        ar = fmaf(hv, Wr[k * 256 + j], ar);
    }
    xl[(size_t)n * 256 + j] = al;
    xr[(size_t)n * 256 + j] = ar;
}

// ---- generic fp32 GEMM: C[M,N] = A[M,K] @ B[K,N] (+ bias), 64x64 tiles ----
__global__ __launch_bounds__(256) void k_gemm(const float* __restrict__ A,
                                              const float* __restrict__ B,
                                              float* __restrict__ C,
                                              const float* __restrict__ bias,
                                              int M, int N, int K) {
    __shared__ float As[16][65];  // [k][m]
    __shared__ float Bs[16][65];  // [k][n]
    int tid = threadIdx.x;
    int tx = tid & 15, ty = tid >> 4;
    int row0 = blockIdx.x * 64, col0 = blockIdx.y * 64;
    float acc[4][4] = {};
    int ar = tid >> 2, ak = (tid & 3) * 4;   // A loader: row ar, 4 k's at ak
    int bk = tid >> 4, bc = (tid & 15) * 4;  // B loader: k-row bk, 4 cols at bc
    for (int k0 = 0; k0 < K; k0 += 16) {
        float4 av = make_float4(0.f, 0.f, 0.f, 0.f);
        if (row0 + ar < M) av = *(const float4*)(A + (size_t)(row0 + ar) * K + k0 + ak);
        As[ak + 0][ar] = av.x; As[ak + 1][ar] = av.y;
        As[ak + 2][ar] = av.z; As[ak + 3][ar] = av.w;
        float4 bv = make_float4(0.f, 0.f, 0.f, 0.f);
        if (col0 + bc < N) bv = *(const float4*)(B + (size_t)(k0 + bk) * N + col0 + bc);
        Bs[bk][bc + 0] = bv.x; Bs[bk][bc + 1] = bv.y;
        Bs[bk][bc + 2] = bv.z; Bs[bk][bc + 3] = bv.w;
        __syncthreads();
#pragma unroll
        for (int kk = 0; kk < 16; kk++) {
            float a0 = As[kk][ty * 4 + 0], a1 = As[kk][ty * 4 + 1];
            float a2 = As[kk][ty * 4 + 2], a3 = As[kk][ty * 4 + 3];
            float b0 = Bs[kk][tx * 4 + 0], b1 = Bs[kk][tx * 4 + 1];
            float b2 = Bs[kk][tx * 4 + 2], b3 = Bs[kk][tx * 4 + 3];
            acc[0][0] = fmaf(a0, b0, acc[0][0]); acc[0][1] = fmaf(a0, b1, acc[0][1]);
            acc[0][2] = fmaf(a0, b2, acc[0][2]); acc[0][3] = fmaf(a0, b3, acc[0][3]);
            acc[1][0] = fmaf(a1, b0, acc[1][0]); acc[1][1] = fmaf(a1, b1, acc[1][1]);
            acc[1][2] = fmaf(a1, b2, acc[1][2]); acc[1][3] = fmaf(a1, b3, acc[1][3]);
            acc[2][0] = fmaf(a2, b0, acc[2][0]); acc[2][1] = fmaf(a2, b1, acc[2][1]);
            acc[2][2] = fmaf(a2, b2, acc[2][2]); acc[2][3] = fmaf(a2, b3, acc[2][3]);
            acc[3][0] = fmaf(a3, b0, acc[3][0]); acc[3][1] = fmaf(a3, b1, acc[3][1]);
            acc[3][2] = fmaf(a3, b2, acc[3][2]); acc[3][3] = fmaf(a3, b3, acc[3][3]);
        }
        __syncthreads();
    }
#pragma unroll
    for (int i = 0; i < 4; i++) {
        int r = row0 + ty * 4 + i;
        if (r >= M) continue;
#pragma unroll
        for (int j = 0; j < 4; j++) {
            int c = col0 + tx * 4 + j;
            if (c >= N) continue;
            float v = acc[i][j];
            if (bias) v += bias[c];
            C[(size_t)r * N + c] = v;
        }
    }
}

// ---- CSR build: histogram of dst ----
__global__ void k_hist(const int* __restrict__ dst, int* __restrict__ cnt) {
    int e = blockIdx.x * blockDim.x + threadIdx.x;
    if (e >= N_EDGES) return;
    atomicAdd(cnt + dst[e], 1);
}

// ---- CSR build: single-block exclusive scan; writes rowptr AND wp (copy) ----
__global__ void k_scan(const int* __restrict__ cnt, int* __restrict__ rowptr,
                       int* __restrict__ wp, int n) {
    __shared__ int buf[256];
    __shared__ int base;
    if (threadIdx.x == 0) base = 0;
    __syncthreads();
    for (int i0 = 0; i0 < n; i0 += 256) {
        int i = i0 + threadIdx.x;
        int v = (i < n) ? cnt[i] : 0;
        buf[threadIdx.x] = v;
        __syncthreads();
#pragma unroll
        for (int off = 1; off < 256; off <<= 1) {
            int t = (threadIdx.x >= off) ? buf[threadIdx.x - off] : 0;
            __syncthreads();
            buf[threadIdx.x] += t;
            __syncthreads();
        }
        if (i < n) {
            int ex = base + buf[threadIdx.x] - v;  // exclusive
            rowptr[i] = ex;
            wp[i] = ex;
        }
        __syncthreads();
        if (threadIdx.x == 0) base += buf[255];
        __syncthreads();
    }
    if (threadIdx.x == 0) rowptr[n] = base;
}

// ---- CSR build: scatter edge ids into per-dst slots ----
__global__ void k_fill(const int* __restrict__ dst, int* __restrict__ wp,
                       int* __restrict__ eidx) {
    int e = blockIdx.x * blockDim.x + threadIdx.x;
    if (e >= N_EDGES) return;
    int p = atomicAdd(wp + dst[e], 1);
    eidx[p] = e;
}

// ---- edge scores + segment max (thread per (edge,head)) ----
__global__ void k_edge_score(const float* __restrict__ xl, const float* __restrict__ xr,
                             const float* __restrict__ ea, const float* __restrict__ We,
                             const float* __restrict__ att, const int* __restrict__ src,
                             const int* __restrict__ dst, float* __restrict__ score,
                             unsigned int* __restrict__ mbuf) {
    int t = blockIdx.x * blockDim.x + threadIdx.x;
    if (t >= N_EDGES * 8) return;
    int e = t >> 3, h = t & 7;
    int s = src[e], d = dst[e];
    float a = ea[e];
    const float4* l4 = (const float4*)(xl + (size_t)s * 256 + h * 32);
    const float4* r4 = (const float4*)(xr + (size_t)d * 256 + h * 32);
    const float4* w4 = (const float4*)(We + h * 32);
    const float4* t4 = (const float4*)(att + h * 32);
    float sc = 0.f;
#pragma unroll
    for (int i = 0; i < 8; i++) {
        float4 lv = l4[i], rv = r4[i], wv = w4[i], av = t4[i];
        float f;
        f = lv.x + rv.x + a * wv.x; f = (f >= 0.f) ? f : 0.2f * f; sc = fmaf(f, av.x, sc);
        f = lv.y + rv.y + a * wv.y; f = (f >= 0.f) ? f : 0.2f * f; sc = fmaf(f, av.y, sc);
        f = lv.z + rv.z + a * wv.z; f = (f >= 0.f) ? f : 0.2f * f; sc = fmaf(f, av.z, sc);
        f = lv.w + rv.w + a * wv.w; f = (f >= 0.f) ? f : 0.2f * f; sc = fmaf(f, av.w, sc);
    }
    score[t] = sc;
    atomicMax(mbuf + (size_t)d * 8 + h, enc_f(sc));
}

// ---- exp(score - max) + segment sum ----
__global__ void k_edge_exp(const int* __restrict__ dst, const unsigned int* __restrict__ mbuf,
                           float* __restrict__ score, float* __restrict__ sbuf) {
    int t = blockIdx.x * blockDim.x + threadIdx.x;
    if (t >= N_EDGES * 8) return;
    int e = t >> 3, h = t & 7;
    int d = dst[e];
    float ex = expf(score[t] - dec_f(mbuf[(size_t)d * 8 + h]));
    score[t] = ex;
    atomicAdd(sbuf + (size_t)d * 8 + h, ex);
}

// ---- CSR gather aggregate: one wave per dst node, no atomics ----
__global__ __launch_bounds__(256) void k_agg_csr(const int* __restrict__ rowptr,
                                                 const int* __restrict__ eidx,
                                                 const int* __restrict__ src,
                                                 const float* __restrict__ ex,
                                                 const float* __restrict__ sbuf,
                                                 const float* __restrict__ xl,
                                                 float* __restrict__ out) {
    int node = blockIdx.x * 4 + (threadIdx.x >> 6);
    if (node >= N_NODES) return;
    int lane = threadIdx.x & 63;
    int h = lane >> 3;  // lane covers dims [4*lane, 4*lane+4) -> head = lane/8
    int beg = rowptr[node], end = rowptr[node + 1];
    float inv_s = 1.0f / (sbuf[(size_t)node * 8 + h] + 1e-16f);
    float4 acc = make_float4(0.f, 0.f, 0.f, 0.f);
    for (int i = beg; i < end; i++) {
        int e = eidx[i];
        float alpha = ex[(size_t)e * 8 + h] * inv_s;
        float4 v = ((const float4*)(xl + (size_t)src[e] * 256))[lane];
        acc.x = fmaf(alpha, v.x, acc.x);
        acc.y = fmaf(alpha, v.y, acc.y);
        acc.z = fmaf(alpha, v.z, acc.z);
        acc.w = fmaf(alpha, v.w, acc.w);
    }
    ((float4*)(out + (size_t)node * 256))[lane] = acc;
}

// ---- LayerNorm over 256 dims, one wave per row: out = LN(in [+res] [+vbias]) * g + b ----
__global__ void k_ln(const float* __restrict__ in, const float* __restrict__ res,
                     const float* __restrict__ vbias, const float* __restrict__ g,
                     const float* __restrict__ b, float* __restrict__ out, int rows) {
    int gt = blockIdx.x * blockDim.x + threadIdx.x;
    int wid = gt >> 6, lane = threadIdx.x & 63;
    if (wid >= rows) return;
    float4 v = ((const float4*)(in + (size_t)wid * 256))[lane];
    if (res) {
        float4 r = ((const float4*)(res + (size_t)wid * 256))[lane];
        v.x += r.x; v.y += r.y; v.z += r.z; v.w += r.w;
    }
    if (vbias) {
        float4 r = ((const float4*)vbias)[lane];
        v.x += r.x; v.y += r.y; v.z += r.z; v.w += r.w;
    }
    float sum = v.x + v.y + v.z + v.w;
#pragma unroll
    for (int o = 32; o > 0; o >>= 1) sum += __shfl_xor(sum, o, 64);
    float mean = sum * (1.0f / 256.0f);
    float dx = v.x - mean, dy = v.y - mean, dz = v.z - mean, dw = v.w - mean;
    float sq = dx * dx + dy * dy + dz * dz + dw * dw;
#pragma unroll
    for (int o = 32; o > 0; o >>= 1) sq += __shfl_xor(sq, o, 64);
    float inv = 1.0f / sqrtf(sq * (1.0f / 256.0f) + 1e-5f);
    float4 gg = ((const float4*)g)[lane];
    float4 bb = ((const float4*)b)[lane];
    float4 o4 = make_float4(dx * inv * gg.x + bb.x, dy * inv * gg.y + bb.y,
                            dz * inv * gg.z + bb.z, dw * inv * gg.w + bb.w);
    ((float4*)(out + (size_t)wid * 256))[lane] = o4;
}

extern "C" void kernel_launch(void* const* d_in, const int* in_sizes, int n_in,
                              void* d_out, int out_size, void* d_ws, size_t ws_size,
                              hipStream_t stream) {
    const float* x_gnn = (const float*)d_in[0];
    const int* ei = (const int*)d_in[1];
    const int* src = ei;
    const int* dst = ei + N_EDGES;
    const float* ea   = (const float*)d_in[2];
    const float* W_in = (const float*)d_in[3];
    const float* b_in = (const float*)d_in[4];
    const float* Wl1  = (const float*)d_in[5];
    const float* Wr1  = (const float*)d_in[6];
    const float* We1  = (const float*)d_in[7];
    const float* att1 = (const float*)d_in[8];
    const float* bg1  = (const float*)d_in[9];
    const float* ln1_g = (const float*)d_in[10];
    const float* ln1_b = (const float*)d_in[11];
    const float* W_down = (const float*)d_in[12];
    const float* lnd_g = (const float*)d_in[13];
    const float* lnd_b = (const float*)d_in[14];
    const float* Wl2  = (const float*)d_in[15];
    const float* Wr2  = (const float*)d_in[16];
    const float* We2  = (const float*)d_in[17];
    const float* att2 = (const float*)d_in[18];
    const float* bg2  = (const float*)d_in[19];
    const float* ln2_g = (const float*)d_in[20];
    const float* ln2_b = (const float*)d_in[21];
    const float* W_up = (const float*)d_in[22];
    const float* lnu_g = (const float*)d_in[23];
    const float* lnu_b = (const float*)d_in[24];
    const float* W_cls = (const float*)d_in[25];
    const float* b_cls = (const float*)d_in[26];

    // workspace layout (floats)
    float* ws = (float*)d_ws;
    float* B_h0 = ws;                                 // 640,000
    float* B_A  = B_h0 + 640000;                      // 5,120,000 (xl1 / xl2 / z2)
    float* B_B  = B_A + 5120000;                      // 5,120,000 (xr1 / xr2 / h2)
    float* B_S  = B_B + 5120000;                      // 2,560,000 (score / ex)
    unsigned int* B_m = (unsigned int*)(B_S + 2560000); // 160,000
    float* B_s  = (float*)(B_m + 160000);             // 160,000
    float* B_C  = B_s + 160000;                       // 5,120,000 (agg1 / zpre / agg2)
    float* B_h1 = B_C + 5120000;                      // 5,120,000
    float* B_z  = B_h1 + 5120000;                     // 5,120,000
    // CSR scratch (ints) after the float pool
    int* C_cnt = (int*)(B_z + 5120000);               // 20,000
    int* C_row = C_cnt + 20000;                       // 20,001
    int* C_wp  = C_row + 20001;                       // 20,000
    int* C_eid = C_wp + 20000;                        // 320,000
    // total: ~117.9 MB

    float* out_logits = (float*)d_out;
    float* out_h = out_logits + (size_t)N_NODES * 1000;

    int eth = N_EDGES * 8;
    int eblk = (eth + 255) / 256;
    int lnblk = (N_NODES * 64 + 255) / 256;
    int aggblk = (N_NODES + 3) / 4;
    dim3 gg((N_NODES + 63) / 64, (256 + 63) / 64);
    dim3 gc((N_NODES + 63) / 64, (1000 + 63) / 64);

    // 0. build CSR over dst (reused by both GAT layers)
    hipMemsetAsync(C_cnt, 0, (size_t)20000 * 4, stream);
    k_hist<<<(N_EDGES + 255) / 256, 256, 0, stream>>>(dst, C_cnt);
    k_scan<<<1, 256, 0, stream>>>(C_cnt, C_row, C_wp, N_NODES);
    k_fill<<<(N_EDGES + 255) / 256, 256, 0, stream>>>(dst, C_wp, C_eid);

    // 1. h0 = x @ W_in + b_in
    k_inproj<<<(N_NODES * 32 + 255) / 256, 256, 0, stream>>>(x_gnn, W_in, b_in, B_h0);
    // 2. xl1 = h0@Wl1, xr1 = h0@Wr1
    k_dual32<<<N_NODES, 256, 0, stream>>>(B_h0, Wl1, Wr1, B_A, B_B);
    // 3. GAT1
    hipMemsetAsync(B_m, 0, (size_t)160000 * 4, stream);
    hipMemsetAsync(B_s, 0, (size_t)160000 * 4, stream);
    k_edge_score<<<eblk, 256, 0, stream>>>(B_A, B_B, ea, We1, att1, src, dst, B_S, B_m);
    k_edge_exp<<<eblk, 256, 0, stream>>>(dst, B_m, B_S, B_s);
    k_agg_csr<<<aggblk, 256, 0, stream>>>(C_row, C_eid, src, B_S, B_s, B_A, B_C);
    // 4. h1 = LN(agg1 + bg1)
    k_ln<<<lnblk, 256, 0, stream>>>(B_C, nullptr, bg1, ln1_g, ln1_b, B_h1, N_NODES);
    // 5. z = LN(h1 @ W_down)
    k_gemm<<<gg, 256, 0, stream>>>(B_h1, W_down, B_C, nullptr, N_NODES, 256, 256);
    k_ln<<<lnblk, 256, 0, stream>>>(B_C, nullptr, nullptr, lnd_g, lnd_b, B_z, N_NODES);
    // 6. GAT2
    k_gemm<<<gg, 256, 0, stream>>>(B_z, Wl2, B_A, nullptr, N_NODES, 256, 256);
    k_gemm<<<gg, 256, 0, stream>>>(B_z, Wr2, B_B, nullptr, N_NODES, 256, 256);
    hipMemsetAsync(B_m, 0, (size_t)160000 * 4, stream);
    hipMemsetAsync(B_s, 0, (size_t)160000 * 4, stream);
    k_edge_score<<<eblk, 256, 0, stream>>>(B_A, B_B, ea, We2, att2, src, dst, B_S, B_m);
    k_edge_exp<<<eblk, 256, 0, stream>>>(dst, B_m, B_S, B_s);
    k_agg_csr<<<aggblk, 256, 0, stream>>>(C_row, C_eid, src, B_S, B_s, B_A, B_C);
    // 7. z2 = LN(agg2 + bg2 + z) -> B_A
    k_ln<<<lnblk, 256, 0, stream>>>(B_C, B_z, bg2, ln2_g, ln2_b, B_A, N_NODES);
    // 8. h2 = z2 @ W_up -> B_B
    k_gemm<<<gg, 256, 0, stream>>>(B_A, W_up, B_B, nullptr, N_NODES, 256, 256);
    // 9. h = LN(h1 + h2) -> out_h
    k_ln<<<lnblk, 256, 0, stream>>>(B_B, B_h1, nullptr, lnu_g, lnu_b, out_h, N_NODES);
    // 10. logits = h @ W_cls + b_cls
    k_gemm<<<gc, 256, 0, stream>>>(out_h, W_cls, out_logits, b_cls, N_NODES, 1000, 256);
}

// Round 3
// 1075.933 us; speedup vs baseline: 8.9780x; 1.2594x over previous
//
#include <hip/hip_runtime.h>
#include <math.h>

#define N_NODES 20000
#define N_EDGES 320000

typedef __attribute__((ext_vector_type(8))) __bf16 bf16x8;
typedef __attribute__((ext_vector_type(8))) unsigned short ushort8;
typedef __attribute__((ext_vector_type(4))) float floatx4;

// ---- fp32 -> bf16 (RNE) raw bits ----
__device__ __forceinline__ unsigned short f2b(float f) {
    unsigned int u = __float_as_uint(f);
    unsigned int r = (u + 0x7fffu + ((u >> 16) & 1u)) >> 16;
    return (unsigned short)r;
}

// ---- ordered-uint encoding for float atomicMax ----
__device__ __forceinline__ unsigned int enc_f(float f) {
    unsigned int u = __float_as_uint(f);
    return (u & 0x80000000u) ? ~u : (u | 0x80000000u);
}
__device__ __forceinline__ float dec_f(unsigned int e) {
    return (e & 0x80000000u) ? __uint_as_float(e & 0x7fffffffu) : __uint_as_float(~e);
}

// ---- in_proj: h0[N,32] = x[N,18] @ W[18,32] + b ----
__global__ void k_inproj(const float* __restrict__ x, const float* __restrict__ W,
                         const float* __restrict__ b, float* __restrict__ h0) {
    int t = blockIdx.x * blockDim.x + threadIdx.x;
    if (t >= N_NODES * 32) return;
    int n = t >> 5, p = t & 31;
    float acc = b[p];
    const float* xr = x + n * 18;
#pragma unroll
    for (int k = 0; k < 18; k++) acc = fmaf(xr[k], W[k * 32 + p], acc);
    h0[t] = acc;
}

// ---- dual GEMM K=32: xl = h0@Wl, xr = h0@Wr (one node per block) ----
__global__ void k_dual32(const float* __restrict__ h0, const float* __restrict__ Wl,
                         const float* __restrict__ Wr, float* __restrict__ xl,
                         float* __restrict__ xr) {
    __shared__ float hs[32];
    int n = blockIdx.x;
    int j = threadIdx.x;
    if (j < 32) hs[j] = h0[n * 32 + j];
    __syncthreads();
    float al = 0.f, ar = 0.f;
#pragma unroll
    for (int k = 0; k < 32; k++) {
        float hv = hs[k];
        al = fmaf(hv, Wl[k * 256 + j], al);
        ar = fmaf(hv, Wr[k * 256 + j], ar);
    }
    xl[(size_t)n * 256 + j] = al;
    xr[(size_t)n * 256 + j] = ar;
}

// ---- weight convert + transpose: W[K=256][N] fp32 -> Wt[N][256] bf16 ----
__global__ void k_wcvt(const float* __restrict__ W, unsigned short* __restrict__ Wt,
                       int Nd) {
    int t = blockIdx.x * blockDim.x + threadIdx.x;
    if (t >= Nd * 256) return;
    int n = t >> 8, k = t & 255;
    Wt[t] = f2b(W[(size_t)k * Nd + n]);
}

// ---- bf16 MFMA GEMM: C[M,N] = A[M,256] @ Bt[N,256]^T (+bias)
// 128x128 block tile, 4 waves 2x2, each wave 4x4 tiles of 16x16x32 MFMA.
// LDS stored in fragment-lane order: [tile][lane][8] -> conflict-free b128.
__global__ __launch_bounds__(256) void k_gemm_bf16(
    const unsigned short* __restrict__ A, const unsigned short* __restrict__ Bt,
    float* __restrict__ C, const float* __restrict__ bias, int M, int N) {
    const int K = 256;
    __shared__ unsigned short As[8 * 64 * 8];
    __shared__ unsigned short Bs[8 * 64 * 8];
    int tid = threadIdx.x;
    int wave = tid >> 6, lane = tid & 63;
    int wr = wave >> 1, wc = wave & 1;
    int row0 = blockIdx.x * 128, col0 = blockIdx.y * 128;
    floatx4 zero4 = {0.f, 0.f, 0.f, 0.f};
    floatx4 acc[4][4];
#pragma unroll
    for (int i = 0; i < 4; i++)
#pragma unroll
        for (int j = 0; j < 4; j++) acc[i][j] = zero4;
    for (int kb = 0; kb < K; kb += 32) {
#pragma unroll
        for (int q = 0; q < 2; q++) {
            int c = tid * 2 + q;           // 0..511
            int row = c >> 2, koff = (c & 3) * 8;
            int lp = (row & 15) + 16 * (koff >> 3);
            int mt = row >> 4;
            ushort8 va = {0, 0, 0, 0, 0, 0, 0, 0};
            if (row0 + row < M)
                va = *(const ushort8*)(A + (size_t)(row0 + row) * K + kb + koff);
            *(ushort8*)(As + (mt * 64 + lp) * 8) = va;
            ushort8 vb = {0, 0, 0, 0, 0, 0, 0, 0};
            if (col0 + row < N)
                vb = *(const ushort8*)(Bt + (size_t)(col0 + row) * K + kb + koff);
            *(ushort8*)(Bs + (mt * 64 + lp) * 8) = vb;
        }
        __syncthreads();
        bf16x8 af[4], bfr[4];
#pragma unroll
        for (int i = 0; i < 4; i++)
            af[i] = *(const bf16x8*)(As + ((wr * 4 + i) * 64 + lane) * 8);
#pragma unroll
        for (int j = 0; j < 4; j++)
            bfr[j] = *(const bf16x8*)(Bs + ((wc * 4 + j) * 64 + lane) * 8);
#pragma unroll
        for (int i = 0; i < 4; i++)
#pragma unroll
            for (int j = 0; j < 4; j++)
                acc[i][j] = __builtin_amdgcn_mfma_f32_16x16x32_bf16(
                    af[i], bfr[j], acc[i][j], 0, 0, 0);
        __syncthreads();
    }
    // epilogue: C/D layout col=lane&15, row=quad*4+reg
    int quad = lane >> 4, nl = lane & 15;
#pragma unroll
    for (int i = 0; i < 4; i++) {
#pragma unroll
        for (int j = 0; j < 4; j++) {
            int col = col0 + wc * 64 + j * 16 + nl;
            if (col >= N) continue;
            float bv = bias ? bias[col] : 0.f;
#pragma unroll
            for (int r = 0; r < 4; r++) {
                int rr = row0 + wr * 64 + i * 16 + quad * 4 + r;
                if (rr < M) C[(size_t)rr * N + col] = acc[i][j][r] + bv;
            }
        }
    }
}

// ---- CSR build: histogram of dst ----
__global__ void k_hist(const int* __restrict__ dst, int* __restrict__ cnt) {
    int e = blockIdx.x * blockDim.x + threadIdx.x;
    if (e >= N_EDGES) return;
    atomicAdd(cnt + dst[e], 1);
}

// ---- CSR build: single-block exclusive scan; writes rowptr AND wp (copy) ----
__global__ void k_scan(const int* __restrict__ cnt, int* __restrict__ rowptr,
                       int* __restrict__ wp, int n) {
    __shared__ int buf[256];
    __shared__ int base;
    if (threadIdx.x == 0) base = 0;
    __syncthreads();
    for (int i0 = 0; i0 < n; i0 += 256) {
        int i = i0 + threadIdx.x;
        int v = (i < n) ? cnt[i] : 0;
        buf[threadIdx.x] = v;
        __syncthreads();
#pragma unroll
        for (int off = 1; off < 256; off <<= 1) {
            int t = (threadIdx.x >= off) ? buf[threadIdx.x - off] : 0;
            __syncthreads();
            buf[threadIdx.x] += t;
            __syncthreads();
        }
        if (i < n) {
            int ex = base + buf[threadIdx.x] - v;  // exclusive
            rowptr[i] = ex;
            wp[i] = ex;
        }
        __syncthreads();
        if (threadIdx.x == 0) base += buf[255];
        __syncthreads();
    }
    if (threadIdx.x == 0) rowptr[n] = base;
}

// ---- CSR build: scatter edge ids into per-dst slots ----
__global__ void k_fill(const int* __restrict__ dst, int* __restrict__ wp,
                       int* __restrict__ eidx) {
    int e = blockIdx.x * blockDim.x + threadIdx.x;
    if (e >= N_EDGES) return;
    int p = atomicAdd(wp + dst[e], 1);
    eidx[p] = e;
}

// ---- edge scores + segment max (thread per (edge,head)) ----
__global__ void k_edge_score(const float* __restrict__ xl, const float* __restrict__ xr,
                             const float* __restrict__ ea, const float* __restrict__ We,
                             const float* __restrict__ att, const int* __restrict__ src,
                             const int* __restrict__ dst, float* __restrict__ score,
                             unsigned int* __restrict__ mbuf) {
    int t = blockIdx.x * blockDim.x + threadIdx.x;
    if (t >= N_EDGES * 8) return;
    int e = t >> 3, h = t & 7;
    int s = src[e], d = dst[e];
    float a = ea[e];
    const float4* l4 = (const float4*)(xl + (size_t)s * 256 + h * 32);
    const float4* r4 = (const float4*)(xr + (size_t)d * 256 + h * 32);
    const float4* w4 = (const float4*)(We + h * 32);
    const float4* t4 = (const float4*)(att + h * 32);
    float sc = 0.f;
#pragma unroll
    for (int i = 0; i < 8; i++) {
        float4 lv = l4[i], rv = r4[i], wv = w4[i], av = t4[i];
        float f;
        f = lv.x + rv.x + a * wv.x; f = (f >= 0.f) ? f : 0.2f * f; sc = fmaf(f, av.x, sc);
        f = lv.y + rv.y + a * wv.y; f = (f >= 0.f) ? f : 0.2f * f; sc = fmaf(f, av.y, sc);
        f = lv.z + rv.z + a * wv.z; f = (f >= 0.f) ? f : 0.2f * f; sc = fmaf(f, av.z, sc);
        f = lv.w + rv.w + a * wv.w; f = (f >= 0.f) ? f : 0.2f * f; sc = fmaf(f, av.w, sc);
    }
    score[t] = sc;
    atomicMax(mbuf + (size_t)d * 8 + h, enc_f(sc));
}

// ---- exp(score - max) + segment sum ----
__global__ void k_edge_exp(const int* __restrict__ dst, const unsigned int* __restrict__ mbuf,
                           float* __restrict__ score, float* __restrict__ sbuf) {
    int t = blockIdx.x * blockDim.x + threadIdx.x;
    if (t >= N_EDGES * 8) return;
    int e = t >> 3, h = t & 7;
    int d = dst[e];
    float ex = expf(score[t] - dec_f(mbuf[(size_t)d * 8 + h]));
    score[t] = ex;
    atomicAdd(sbuf + (size_t)d * 8 + h, ex);
}

// ---- CSR gather aggregate: one wave per dst node, no atomics ----
__global__ __launch_bounds__(256) void k_agg_csr(const int* __restrict__ rowptr,
                                                 const int* __restrict__ eidx,
                                                 const int* __restrict__ src,
                                                 const float* __restrict__ ex,
                                                 const float* __restrict__ sbuf,
                                                 const float* __restrict__ xl,
                                                 float* __restrict__ out) {
    int node = blockIdx.x * 4 + (threadIdx.x >> 6);
    if (node >= N_NODES) return;
    int lane = threadIdx.x & 63;
    int h = lane >> 3;
    int beg = rowptr[node], end = rowptr[node + 1];
    float inv_s = 1.0f / (sbuf[(size_t)node * 8 + h] + 1e-16f);
    float4 acc = make_float4(0.f, 0.f, 0.f, 0.f);
    for (int i = beg; i < end; i++) {
        int e = eidx[i];
        float alpha = ex[(size_t)e * 8 + h] * inv_s;
        float4 v = ((const float4*)(xl + (size_t)src[e] * 256))[lane];
        acc.x = fmaf(alpha, v.x, acc.x);
        acc.y = fmaf(alpha, v.y, acc.y);
        acc.z = fmaf(alpha, v.z, acc.z);
        acc.w = fmaf(alpha, v.w, acc.w);
    }
    ((float4*)(out + (size_t)node * 256))[lane] = acc;
}

// ---- LayerNorm over 256 dims, one wave per row ----
// out = LN(in [+res] [+vbias]) * g + b; optional fp32 out + optional bf16 out
__global__ void k_ln(const float* __restrict__ in, const float* __restrict__ res,
                     const float* __restrict__ vbias, const float* __restrict__ g,
                     const float* __restrict__ b, float* __restrict__ outf,
                     unsigned short* __restrict__ outb, int rows) {
    int gt = blockIdx.x * blockDim.x + threadIdx.x;
    int wid = gt >> 6, lane = threadIdx.x & 63;
    if (wid >= rows) return;
    float4 v = ((const float4*)(in + (size_t)wid * 256))[lane];
    if (res) {
        float4 r = ((const float4*)(res + (size_t)wid * 256))[lane];
        v.x += r.x; v.y += r.y; v.z += r.z; v.w += r.w;
    }
    if (vbias) {
        float4 r = ((const float4*)vbias)[lane];
        v.x += r.x; v.y += r.y; v.z += r.z; v.w += r.w;
    }
    float sum = v.x + v.y + v.z + v.w;
#pragma unroll
    for (int o = 32; o > 0; o >>= 1) sum += __shfl_xor(sum, o, 64);
    float mean = sum * (1.0f / 256.0f);
    float dx = v.x - mean, dy = v.y - mean, dz = v.z - mean, dw = v.w - mean;
    float sq = dx * dx + dy * dy + dz * dz + dw * dw;
#pragma unroll
    for (int o = 32; o > 0; o >>= 1) sq += __shfl_xor(sq, o, 64);
    float inv = 1.0f / sqrtf(sq * (1.0f / 256.0f) + 1e-5f);
    float4 gg = ((const float4*)g)[lane];
    float4 bb = ((const float4*)b)[lane];
    float4 o4 = make_float4(dx * inv * gg.x + bb.x, dy * inv * gg.y + bb.y,
                            dz * inv * gg.z + bb.z, dw * inv * gg.w + bb.w);
    if (outf) ((float4*)(outf + (size_t)wid * 256))[lane] = o4;
    if (outb) {
        ushort4 u;
        u.x = f2b(o4.x); u.y = f2b(o4.y); u.z = f2b(o4.z); u.w = f2b(o4.w);
        ((ushort4*)(outb + (size_t)wid * 256))[lane] = u;
    }
}

extern "C" void kernel_launch(void* const* d_in, const int* in_sizes, int n_in,
                              void* d_out, int out_size, void* d_ws, size_t ws_size,
                              hipStream_t stream) {
    const float* x_gnn = (const float*)d_in[0];
    const int* ei = (const int*)d_in[1];
    const int* src = ei;
    const int* dst = ei + N_EDGES;
    const float* ea   = (const float*)d_in[2];
    const float* W_in = (const float*)d_in[3];
    const float* b_in = (const float*)d_in[4];
    const float* Wl1  = (const float*)d_in[5];
    const float* Wr1  = (const float*)d_in[6];
    const float* We1  = (const float*)d_in[7];
    const float* att1 = (const float*)d_in[8];
    const float* bg1  = (const float*)d_in[9];
    const float* ln1_g = (const float*)d_in[10];
    const float* ln1_b = (const float*)d_in[11];
    const float* W_down = (const float*)d_in[12];
    const float* lnd_g = (const float*)d_in[13];
    const float* lnd_b = (const float*)d_in[14];
    const float* Wl2  = (const float*)d_in[15];
    const float* Wr2  = (const float*)d_in[16];
    const float* We2  = (const float*)d_in[17];
    const float* att2 = (const float*)d_in[18];
    const float* bg2  = (const float*)d_in[19];
    const float* ln2_g = (const float*)d_in[20];
    const float* ln2_b = (const float*)d_in[21];
    const float* W_up = (const float*)d_in[22];
    const float* lnu_g = (const float*)d_in[23];
    const float* lnu_b = (const float*)d_in[24];
    const float* W_cls = (const float*)d_in[25];
    const float* b_cls = (const float*)d_in[26];

    // workspace layout (floats)
    float* ws = (float*)d_ws;
    float* B_h0 = ws;                                 // 640,000
    float* B_A  = B_h0 + 640000;                      // 5,120,000 (xl1 / xl2)
    float* B_B  = B_A + 5120000;                      // 5,120,000 (xr1 / xr2 / h2)
    float* B_S  = B_B + 5120000;                      // 2,560,000 (score/ex; later z2_bf16 then h_bf16)
    unsigned int* B_m = (unsigned int*)(B_S + 2560000); // 160,000
    float* B_s  = (float*)(B_m + 160000);             // 160,000
    float* B_C  = B_s + 160000;                       // 5,120,000 (agg1 / zpre / agg2)
    float* B_h1 = B_C + 5120000;                      // 5,120,000
    float* B_z  = B_h1 + 5120000;                     // 5,120,000
    float* B_actb = B_z + 5120000;                    // 2,560,000 (bf16 acts: h1b then zb)
    // bf16 weight buffers (ushorts)
    unsigned short* Wt_down = (unsigned short*)(B_actb + 2560000);  // 65,536
    unsigned short* Wt_l2 = Wt_down + 65536;
    unsigned short* Wt_r2 = Wt_l2 + 65536;
    unsigned short* Wt_up = Wt_r2 + 65536;
    unsigned short* Wt_cls = Wt_up + 65536;           // 256,000
    // CSR scratch (ints)
    int* C_cnt = (int*)(Wt_cls + 256000);             // 20,000
    int* C_row = C_cnt + 20000;                       // 20,001
    int* C_wp  = C_row + 20001;                       // 20,000
    int* C_eid = C_wp + 20000;                        // 320,000

    unsigned short* B_hib = (unsigned short*)B_actb;  // h1 bf16, then z bf16 (sequential reuse)
    unsigned short* B_z2b = (unsigned short*)B_S;     // z2 bf16 (after scores dead)
    unsigned short* B_hb  = (unsigned short*)B_S;     // h bf16 (after z2b dead)

    float* out_logits = (float*)d_out;
    float* out_h = out_logits + (size_t)N_NODES * 1000;

    int eth = N_EDGES * 8;
    int eblk = (eth + 255) / 256;
    int lnblk = (N_NODES * 64 + 255) / 256;
    int aggblk = (N_NODES + 3) / 4;
    dim3 gg((N_NODES + 127) / 128, 2);   // N=256
    dim3 gc((N_NODES + 127) / 128, 8);   // N=1000

    // 0. build CSR over dst (reused by both GAT layers)
    hipMemsetAsync(C_cnt, 0, (size_t)20000 * 4, stream);
    k_hist<<<(N_EDGES + 255) / 256, 256, 0, stream>>>(dst, C_cnt);
    k_scan<<<1, 256, 0, stream>>>(C_cnt, C_row, C_wp, N_NODES);
    k_fill<<<(N_EDGES + 255) / 256, 256, 0, stream>>>(dst, C_wp, C_eid);

    // 0b. weight convert+transpose to bf16 [N][K]
    k_wcvt<<<(65536 + 255) / 256, 256, 0, stream>>>(W_down, Wt_down, 256);
    k_wcvt<<<(65536 + 255) / 256, 256, 0, stream>>>(Wl2, Wt_l2, 256);
    k_wcvt<<<(65536 + 255) / 256, 256, 0, stream>>>(Wr2, Wt_r2, 256);
    k_wcvt<<<(65536 + 255) / 256, 256, 0, stream>>>(W_up, Wt_up, 256);
    k_wcvt<<<(256000 + 255) / 256, 256, 0, stream>>>(W_cls, Wt_cls, 1000);

    // 1. h0 = x @ W_in + b_in
    k_inproj<<<(N_NODES * 32 + 255) / 256, 256, 0, stream>>>(x_gnn, W_in, b_in, B_h0);
    // 2. xl1 = h0@Wl1, xr1 = h0@Wr1
    k_dual32<<<N_NODES, 256, 0, stream>>>(B_h0, Wl1, Wr1, B_A, B_B);
    // 3. GAT1
    hipMemsetAsync(B_m, 0, (size_t)160000 * 4, stream);
    hipMemsetAsync(B_s, 0, (size_t)160000 * 4, stream);
    k_edge_score<<<eblk, 256, 0, stream>>>(B_A, B_B, ea, We1, att1, src, dst, B_S, B_m);
    k_edge_exp<<<eblk, 256, 0, stream>>>(dst, B_m, B_S, B_s);
    k_agg_csr<<<aggblk, 256, 0, stream>>>(C_row, C_eid, src, B_S, B_s, B_A, B_C);
    // 4. h1 = LN(agg1 + bg1)  (fp32 + bf16)
    k_ln<<<lnblk, 256, 0, stream>>>(B_C, nullptr, bg1, ln1_g, ln1_b, B_h1, B_hib, N_NODES);
    // 5. z = LN(h1 @ W_down)
    k_gemm_bf16<<<gg, 256, 0, stream>>>(B_hib, Wt_down, B_C, nullptr, N_NODES, 256);
    k_ln<<<lnblk, 256, 0, stream>>>(B_C, nullptr, nullptr, lnd_g, lnd_b, B_z, B_hib, N_NODES);
    // 6. GAT2
    k_gemm_bf16<<<gg, 256, 0, stream>>>(B_hib, Wt_l2, B_A, nullptr, N_NODES, 256);
    k_gemm_bf16<<<gg, 256, 0, stream>>>(B_hib, Wt_r2, B_B, nullptr, N_NODES, 256);
    hipMemsetAsync(B_m, 0, (size_t)160000 * 4, stream);
    hipMemsetAsync(B_s, 0, (size_t)160000 * 4, stream);
    k_edge_score<<<eblk, 256, 0, stream>>>(B_A, B_B, ea, We2, att2, src, dst, B_S, B_m);
    k_edge_exp<<<eblk, 256, 0, stream>>>(dst, B_m, B_S, B_s);
    k_agg_csr<<<aggblk, 256, 0, stream>>>(C_row, C_eid, src, B_S, B_s, B_A, B_C);
    // 7. z2 = LN(agg2 + bg2 + z) -> bf16 only (scores in B_S are dead now)
    k_ln<<<lnblk, 256, 0, stream>>>(B_C, B_z, bg2, ln2_g, ln2_b, nullptr, B_z2b, N_NODES);
    // 8. h2 = z2 @ W_up -> B_B (xr2 dead)
    k_gemm_bf16<<<gg, 256, 0, stream>>>(B_z2b, Wt_up, B_B, nullptr, N_NODES, 256);
    // 9. h = LN(h1 + h2) -> out_h (fp32) + bf16 (reuses B_S after z2b dead)
    k_ln<<<lnblk, 256, 0, stream>>>(B_B, B_h1, nullptr, lnu_g, lnu_b, out_h, B_hb, N_NODES);
    // 10. logits = h @ W_cls + b_cls
    k_gemm_bf16<<<gc, 256, 0, stream>>>(B_hb, Wt_cls, out_logits, b_cls, N_NODES, 1000);
}

// Round 4
// 637.183 us; speedup vs baseline: 15.1601x; 1.6886x over previous
//
#include <hip/hip_runtime.h>
#include <math.h>

#define N_NODES 20000
#define N_EDGES 320000

typedef __attribute__((ext_vector_type(8))) __bf16 bf16x8;
typedef __attribute__((ext_vector_type(8))) unsigned short ushort8;
typedef __attribute__((ext_vector_type(4))) float floatx4;

// ---- fp32 -> bf16 (RNE) raw bits ----
__device__ __forceinline__ unsigned short f2b(float f) {
    unsigned int u = __float_as_uint(f);
    unsigned int r = (u + 0x7fffu + ((u >> 16) & 1u)) >> 16;
    return (unsigned short)r;
}
// ---- bf16 bits -> fp32 ----
__device__ __forceinline__ float b2f(unsigned short u) {
    return __uint_as_float(((unsigned int)u) << 16);
}

// ---- in_proj: h0[N,32] = x[N,18] @ W[18,32] + b  (bf16 out) ----
__global__ void k_inproj(const float* __restrict__ x, const float* __restrict__ W,
                         const float* __restrict__ b, unsigned short* __restrict__ h0) {
    int t = blockIdx.x * blockDim.x + threadIdx.x;
    if (t >= N_NODES * 32) return;
    int n = t >> 5, p = t & 31;
    float acc = b[p];
    const float* xr = x + n * 18;
#pragma unroll
    for (int k = 0; k < 18; k++) acc = fmaf(xr[k], W[k * 32 + p], acc);
    h0[t] = f2b(acc);
}

// ---- weight convert + transpose: W[K][N] fp32 -> Wt[N][K] bf16 ----
__global__ void k_wcvt(const float* __restrict__ W, unsigned short* __restrict__ Wt,
                       int Nd, int K) {
    int t = blockIdx.x * blockDim.x + threadIdx.x;
    if (t >= Nd * K) return;
    int n = t / K, k = t % K;
    Wt[t] = f2b(W[(size_t)k * Nd + n]);
}

// ---- bf16 MFMA GEMM: C[M,N] = A[M,K] @ Bt[N,K]^T (+bias), K multiple of 32
// 128x128 block tile, 4 waves 2x2, each wave 4x4 tiles of 16x16x32 MFMA.
// LDS in fragment-lane order -> conflict-free ds_read_b128.
// Output: Cf (fp32) if non-null, else Cb (bf16).
__global__ __launch_bounds__(256) void k_gemm_bf16(
    const unsigned short* __restrict__ A, const unsigned short* __restrict__ Bt,
    float* __restrict__ Cf, unsigned short* __restrict__ Cb,
    const float* __restrict__ bias, int M, int N, int K) {
    __shared__ unsigned short As[8 * 64 * 8];
    __shared__ unsigned short Bs[8 * 64 * 8];
    int tid = threadIdx.x;
    int wave = tid >> 6, lane = tid & 63;
    int wr = wave >> 1, wc = wave & 1;
    int row0 = blockIdx.x * 128, col0 = blockIdx.y * 128;
    floatx4 zero4 = {0.f, 0.f, 0.f, 0.f};
    floatx4 acc[4][4];
#pragma unroll
    for (int i = 0; i < 4; i++)
#pragma unroll
        for (int j = 0; j < 4; j++) acc[i][j] = zero4;
    for (int kb = 0; kb < K; kb += 32) {
#pragma unroll
        for (int q = 0; q < 2; q++) {
            int c = tid * 2 + q;           // 0..511
            int row = c >> 2, koff = (c & 3) * 8;
            int lp = (row & 15) + 16 * (koff >> 3);
            int mt = row >> 4;
            ushort8 va = {0, 0, 0, 0, 0, 0, 0, 0};
            if (row0 + row < M)
                va = *(const ushort8*)(A + (size_t)(row0 + row) * K + kb + koff);
            *(ushort8*)(As + (mt * 64 + lp) * 8) = va;
            ushort8 vb = {0, 0, 0, 0, 0, 0, 0, 0};
            if (col0 + row < N)
                vb = *(const ushort8*)(Bt + (size_t)(col0 + row) * K + kb + koff);
            *(ushort8*)(Bs + (mt * 64 + lp) * 8) = vb;
        }
        __syncthreads();
        bf16x8 af[4], bfr[4];
#pragma unroll
        for (int i = 0; i < 4; i++)
            af[i] = *(const bf16x8*)(As + ((wr * 4 + i) * 64 + lane) * 8);
#pragma unroll
        for (int j = 0; j < 4; j++)
            bfr[j] = *(const bf16x8*)(Bs + ((wc * 4 + j) * 64 + lane) * 8);
#pragma unroll
        for (int i = 0; i < 4; i++)
#pragma unroll
            for (int j = 0; j < 4; j++)
                acc[i][j] = __builtin_amdgcn_mfma_f32_16x16x32_bf16(
                    af[i], bfr[j], acc[i][j], 0, 0, 0);
        __syncthreads();
    }
    // epilogue: C/D layout col=lane&15, row=quad*4+reg
    int quad = lane >> 4, nl = lane & 15;
#pragma unroll
    for (int i = 0; i < 4; i++) {
#pragma unroll
        for (int j = 0; j < 4; j++) {
            int col = col0 + wc * 64 + j * 16 + nl;
            if (col >= N) continue;
            float bv = bias ? bias[col] : 0.f;
#pragma unroll
            for (int r = 0; r < 4; r++) {
                int rr = row0 + wr * 64 + i * 16 + quad * 4 + r;
                if (rr >= M) continue;
                float v = acc[i][j][r] + bv;
                if (Cf) Cf[(size_t)rr * N + col] = v;
                else Cb[(size_t)rr * N + col] = f2b(v);
            }
        }
    }
}

// ---- CSR build: histogram of dst ----
__global__ void k_hist(const int* __restrict__ dst, int* __restrict__ cnt) {
    int e = blockIdx.x * blockDim.x + threadIdx.x;
    if (e >= N_EDGES) return;
    atomicAdd(cnt + dst[e], 1);
}

// ---- CSR build: single-block exclusive scan; writes rowptr AND wp (copy) ----
__global__ void k_scan(const int* __restrict__ cnt, int* __restrict__ rowptr,
                       int* __restrict__ wp, int n) {
    __shared__ int buf[256];
    __shared__ int base;
    if (threadIdx.x == 0) base = 0;
    __syncthreads();
    for (int i0 = 0; i0 < n; i0 += 256) {
        int i = i0 + threadIdx.x;
        int v = (i < n) ? cnt[i] : 0;
        buf[threadIdx.x] = v;
        __syncthreads();
#pragma unroll
        for (int off = 1; off < 256; off <<= 1) {
            int t = (threadIdx.x >= off) ? buf[threadIdx.x - off] : 0;
            __syncthreads();
            buf[threadIdx.x] += t;
            __syncthreads();
        }
        if (i < n) {
            int ex = base + buf[threadIdx.x] - v;  // exclusive
            rowptr[i] = ex;
            wp[i] = ex;
        }
        __syncthreads();
        if (threadIdx.x == 0) base += buf[255];
        __syncthreads();
    }
    if (threadIdx.x == 0) rowptr[n] = base;
}

// ---- CSR build: scatter edge ids into per-dst slots ----
__global__ void k_fill(const int* __restrict__ dst, int* __restrict__ wp,
                       int* __restrict__ eidx) {
    int e = blockIdx.x * blockDim.x + threadIdx.x;
    if (e >= N_EDGES) return;
    int p = atomicAdd(wp + dst[e], 1);
    eidx[p] = e;
}

// ---- fused GATv2 edge phase: wave per dst node, online softmax, no atomics
// score_h = att_h . leaky_relu(xl[src] + xr[dst] + ea*We), softmax over edges,
// out[dst] = sum alpha * xl[src].  xl/xr bf16, out fp32.
__global__ __launch_bounds__(256) void k_gat_fused(
    const int* __restrict__ rowptr, const int* __restrict__ eidx,
    const int* __restrict__ src, const float* __restrict__ ea,
    const unsigned short* __restrict__ xl, const unsigned short* __restrict__ xr,
    const float* __restrict__ We, const float* __restrict__ att,
    float* __restrict__ out) {
    int node = blockIdx.x * 4 + (threadIdx.x >> 6);
    if (node >= N_NODES) return;
    int lane = threadIdx.x & 63;  // lane covers dims [4*lane, 4*lane+4); head = lane>>3
    float4 wv = ((const float4*)We)[lane];
    float4 av = ((const float4*)att)[lane];
    ushort4 xru = ((const ushort4*)(xr + (size_t)node * 256))[lane];
    float4 rv = make_float4(b2f(xru.x), b2f(xru.y), b2f(xru.z), b2f(xru.w));
    int beg = rowptr[node], end = rowptr[node + 1];
    float m = -3.0e38f, l = 0.f;
    float4 acc = make_float4(0.f, 0.f, 0.f, 0.f);
    for (int i = beg; i < end; i++) {
        int e = eidx[i];
        int s = src[e];
        float a = ea[e];
        ushort4 xlu = ((const ushort4*)(xl + (size_t)s * 256))[lane];
        float4 lv = make_float4(b2f(xlu.x), b2f(xlu.y), b2f(xlu.z), b2f(xlu.w));
        float f, p = 0.f;
        f = lv.x + rv.x + a * wv.x; f = (f >= 0.f) ? f : 0.2f * f; p = fmaf(f, av.x, p);
        f = lv.y + rv.y + a * wv.y; f = (f >= 0.f) ? f : 0.2f * f; p = fmaf(f, av.y, p);
        f = lv.z + rv.z + a * wv.z; f = (f >= 0.f) ? f : 0.2f * f; p = fmaf(f, av.z, p);
        f = lv.w + rv.w + a * wv.w; f = (f >= 0.f) ? f : 0.2f * f; p = fmaf(f, av.w, p);
        // reduce over the 8 lanes of this head
        p += __shfl_xor(p, 1, 64);
        p += __shfl_xor(p, 2, 64);
        p += __shfl_xor(p, 4, 64);
        float mnew = fmaxf(m, p);
        float scale = __expf(m - mnew);
        float w = __expf(p - mnew);
        acc.x = fmaf(acc.x, scale, w * lv.x);
        acc.y = fmaf(acc.y, scale, w * lv.y);
        acc.z = fmaf(acc.z, scale, w * lv.z);
        acc.w = fmaf(acc.w, scale, w * lv.w);
        l = fmaf(l, scale, w);
        m = mnew;
    }
    float inv = 1.0f / (l + 1e-16f);
    ((float4*)(out + (size_t)node * 256))[lane] =
        make_float4(acc.x * inv, acc.y * inv, acc.z * inv, acc.w * inv);
}

// ---- LayerNorm over 256 dims, one wave per row ----
// out = LN(in [+res] [+vbias]) * g + b; optional fp32 out + optional bf16 out
__global__ void k_ln(const float* __restrict__ in, const float* __restrict__ res,
                     const float* __restrict__ vbias, const float* __restrict__ g,
                     const float* __restrict__ b, float* __restrict__ outf,
                     unsigned short* __restrict__ outb, int rows) {
    int gt = blockIdx.x * blockDim.x + threadIdx.x;
    int wid = gt >> 6, lane = threadIdx.x & 63;
    if (wid >= rows) return;
    float4 v = ((const float4*)(in + (size_t)wid * 256))[lane];
    if (res) {
        float4 r = ((const float4*)(res + (size_t)wid * 256))[lane];
        v.x += r.x; v.y += r.y; v.z += r.z; v.w += r.w;
    }
    if (vbias) {
        float4 r = ((const float4*)vbias)[lane];
        v.x += r.x; v.y += r.y; v.z += r.z; v.w += r.w;
    }
    float sum = v.x + v.y + v.z + v.w;
#pragma unroll
    for (int o = 32; o > 0; o >>= 1) sum += __shfl_xor(sum, o, 64);
    float mean = sum * (1.0f / 256.0f);
    float dx = v.x - mean, dy = v.y - mean, dz = v.z - mean, dw = v.w - mean;
    float sq = dx * dx + dy * dy + dz * dz + dw * dw;
#pragma unroll
    for (int o = 32; o > 0; o >>= 1) sq += __shfl_xor(sq, o, 64);
    float inv = 1.0f / sqrtf(sq * (1.0f / 256.0f) + 1e-5f);
    float4 gg = ((const float4*)g)[lane];
    float4 bb = ((const float4*)b)[lane];
    float4 o4 = make_float4(dx * inv * gg.x + bb.x, dy * inv * gg.y + bb.y,
                            dz * inv * gg.z + bb.z, dw * inv * gg.w + bb.w);
    if (outf) ((float4*)(outf + (size_t)wid * 256))[lane] = o4;
    if (outb) {
        ushort4 u;
        u.x = f2b(o4.x); u.y = f2b(o4.y); u.z = f2b(o4.z); u.w = f2b(o4.w);
        ((ushort4*)(outb + (size_t)wid * 256))[lane] = u;
    }
}

extern "C" void kernel_launch(void* const* d_in, const int* in_sizes, int n_in,
                              void* d_out, int out_size, void* d_ws, size_t ws_size,
                              hipStream_t stream) {
    const float* x_gnn = (const float*)d_in[0];
    const int* ei = (const int*)d_in[1];
    const int* src = ei;
    const int* dst = ei + N_EDGES;
    const float* ea   = (const float*)d_in[2];
    const float* W_in = (const float*)d_in[3];
    const float* b_in = (const float*)d_in[4];
    const float* Wl1  = (const float*)d_in[5];
    const float* Wr1  = (const float*)d_in[6];
    const float* We1  = (const float*)d_in[7];
    const float* att1 = (const float*)d_in[8];
    const float* bg1  = (const float*)d_in[9];
    const float* ln1_g = (const float*)d_in[10];
    const float* ln1_b = (const float*)d_in[11];
    const float* W_down = (const float*)d_in[12];
    const float* lnd_g = (const float*)d_in[13];
    const float* lnd_b = (const float*)d_in[14];
    const float* Wl2  = (const float*)d_in[15];
    const float* Wr2  = (const float*)d_in[16];
    const float* We2  = (const float*)d_in[17];
    const float* att2 = (const float*)d_in[18];
    const float* bg2  = (const float*)d_in[19];
    const float* ln2_g = (const float*)d_in[20];
    const float* ln2_b = (const float*)d_in[21];
    const float* W_up = (const float*)d_in[22];
    const float* lnu_g = (const float*)d_in[23];
    const float* lnu_b = (const float*)d_in[24];
    const float* W_cls = (const float*)d_in[25];
    const float* b_cls = (const float*)d_in[26];

    // ---- workspace layout ----
    float* ws = (float*)d_ws;
    float* B_agg = ws;                                // 5,120,000 f (agg / gemm fp32 out)
    float* B_h1  = B_agg + 5120000;                   // 5,120,000 f
    float* B_z   = B_h1 + 5120000;                    // 5,120,000 f
    unsigned short* B_xl = (unsigned short*)(B_z + 5120000);   // 5,120,000 us
    unsigned short* B_xr = B_xl + 5120000;                     // 5,120,000 us
    unsigned short* B_actb = B_xr + 5120000;                   // 5,120,000 us (h1b/zb/z2b/hb seq)
    unsigned short* B_h0b = B_actb + 5120000;                  // 640,000 us
    unsigned short* Wt_l1 = B_h0b + 640000;                    // 8,192
    unsigned short* Wt_r1 = Wt_l1 + 8192;                      // 8,192
    unsigned short* Wt_down = Wt_r1 + 8192;                    // 65,536
    unsigned short* Wt_l2 = Wt_down + 65536;
    unsigned short* Wt_r2 = Wt_l2 + 65536;
    unsigned short* Wt_up = Wt_r2 + 65536;
    unsigned short* Wt_cls = Wt_up + 65536;                    // 256,000
    int* C_cnt = (int*)(Wt_cls + 256000 + (256000 & 1));       // 20,000 (aligned)
    int* C_row = C_cnt + 20000;                                // 20,001
    int* C_wp  = C_row + 20001;                                // 20,000
    int* C_eid = C_wp + 20000;                                 // 320,000

    float* out_logits = (float*)d_out;
    float* out_h = out_logits + (size_t)N_NODES * 1000;

    int lnblk = (N_NODES * 64 + 255) / 256;
    int gatblk = (N_NODES + 3) / 4;
    dim3 gg((N_NODES + 127) / 128, 2);   // N=256
    dim3 gc((N_NODES + 127) / 128, 8);   // N=1000

    // 0. build CSR over dst (reused by both GAT layers)
    hipMemsetAsync(C_cnt, 0, (size_t)20000 * 4, stream);
    k_hist<<<(N_EDGES + 255) / 256, 256, 0, stream>>>(dst, C_cnt);
    k_scan<<<1, 256, 0, stream>>>(C_cnt, C_row, C_wp, N_NODES);
    k_fill<<<(N_EDGES + 255) / 256, 256, 0, stream>>>(dst, C_wp, C_eid);

    // 0b. weight convert+transpose to bf16 [N][K]
    k_wcvt<<<(8192 + 255) / 256, 256, 0, stream>>>(Wl1, Wt_l1, 256, 32);
    k_wcvt<<<(8192 + 255) / 256, 256, 0, stream>>>(Wr1, Wt_r1, 256, 32);
    k_wcvt<<<(65536 + 255) / 256, 256, 0, stream>>>(W_down, Wt_down, 256, 256);
    k_wcvt<<<(65536 + 255) / 256, 256, 0, stream>>>(Wl2, Wt_l2, 256, 256);
    k_wcvt<<<(65536 + 255) / 256, 256, 0, stream>>>(Wr2, Wt_r2, 256, 256);
    k_wcvt<<<(65536 + 255) / 256, 256, 0, stream>>>(W_up, Wt_up, 256, 256);
    k_wcvt<<<(256000 + 255) / 256, 256, 0, stream>>>(W_cls, Wt_cls, 1000, 256);

    // 1. h0 = x @ W_in + b_in (bf16)
    k_inproj<<<(N_NODES * 32 + 255) / 256, 256, 0, stream>>>(x_gnn, W_in, b_in, B_h0b);
    // 2. xl1 = h0@Wl1, xr1 = h0@Wr1 (K=32 MFMA, bf16 out)
    k_gemm_bf16<<<gg, 256, 0, stream>>>(B_h0b, Wt_l1, nullptr, B_xl, nullptr, N_NODES, 256, 32);
    k_gemm_bf16<<<gg, 256, 0, stream>>>(B_h0b, Wt_r1, nullptr, B_xr, nullptr, N_NODES, 256, 32);
    // 3. GAT1 fused -> B_agg
    k_gat_fused<<<gatblk, 256, 0, stream>>>(C_row, C_eid, src, ea, B_xl, B_xr, We1, att1, B_agg);
    // 4. h1 = LN(agg1 + bg1) (fp32 + bf16)
    k_ln<<<lnblk, 256, 0, stream>>>(B_agg, nullptr, bg1, ln1_g, ln1_b, B_h1, B_actb, N_NODES);
    // 5. z = LN(h1 @ W_down)
    k_gemm_bf16<<<gg, 256, 0, stream>>>(B_actb, Wt_down, B_agg, nullptr, nullptr, N_NODES, 256, 256);
    k_ln<<<lnblk, 256, 0, stream>>>(B_agg, nullptr, nullptr, lnd_g, lnd_b, B_z, B_actb, N_NODES);
    // 6. xl2/xr2 (bf16 out) + GAT2 fused
    k_gemm_bf16<<<gg, 256, 0, stream>>>(B_actb, Wt_l2, nullptr, B_xl, nullptr, N_NODES, 256, 256);
    k_gemm_bf16<<<gg, 256, 0, stream>>>(B_actb, Wt_r2, nullptr, B_xr, nullptr, N_NODES, 256, 256);
    k_gat_fused<<<gatblk, 256, 0, stream>>>(C_row, C_eid, src, ea, B_xl, B_xr, We2, att2, B_agg);
    // 7. z2 = LN(agg2 + bg2 + z) -> bf16 only
    k_ln<<<lnblk, 256, 0, stream>>>(B_agg, B_z, bg2, ln2_g, ln2_b, nullptr, B_actb, N_NODES);
    // 8. h2 = z2 @ W_up -> B_agg
    k_gemm_bf16<<<gg, 256, 0, stream>>>(B_actb, Wt_up, B_agg, nullptr, nullptr, N_NODES, 256, 256);
    // 9. h = LN(h2 + h1) -> out_h (fp32) + bf16
    k_ln<<<lnblk, 256, 0, stream>>>(B_agg, B_h1, nullptr, lnu_g, lnu_b, out_h, B_actb, N_NODES);
    // 10. logits = h @ W_cls + b_cls
    k_gemm_bf16<<<gc, 256, 0, stream>>>(B_actb, Wt_cls, out_logits, nullptr, b_cls, N_NODES, 1000, 256);
}

// Round 5
// 567.383 us; speedup vs baseline: 17.0251x; 1.1230x over previous
//
#include <hip/hip_runtime.h>
#include <math.h>

#define N_NODES 20000
#define N_EDGES 320000

typedef __attribute__((ext_vector_type(8))) __bf16 bf16x8;
typedef __attribute__((ext_vector_type(8))) unsigned short ushort8;
typedef __attribute__((ext_vector_type(4))) float floatx4;

// ---- fp32 -> bf16 (RNE) raw bits ----
__device__ __forceinline__ unsigned short f2b(float f) {
    unsigned int u = __float_as_uint(f);
    unsigned int r = (u + 0x7fffu + ((u >> 16) & 1u)) >> 16;
    return (unsigned short)r;
}
// ---- bf16 bits -> fp32 ----
__device__ __forceinline__ float b2f(unsigned short u) {
    return __uint_as_float(((unsigned int)u) << 16);
}

// ---- in_proj: h0[N,32] = x[N,18] @ W[18,32] + b  (bf16 out) ----
__global__ void k_inproj(const float* __restrict__ x, const float* __restrict__ W,
                         const float* __restrict__ b, unsigned short* __restrict__ h0) {
    int t = blockIdx.x * blockDim.x + threadIdx.x;
    if (t >= N_NODES * 32) return;
    int n = t >> 5, p = t & 31;
    float acc = b[p];
    const float* xr = x + n * 18;
#pragma unroll
    for (int k = 0; k < 18; k++) acc = fmaf(xr[k], W[k * 32 + p], acc);
    h0[t] = f2b(acc);
}

// ---- merged weight convert+transpose: all 7 weights in one launch ----
// W[K][N] fp32 -> Wt[N][K] bf16
__global__ void k_wcvt_all(const float* __restrict__ Wl1, const float* __restrict__ Wr1,
                           const float* __restrict__ Wdn, const float* __restrict__ Wl2,
                           const float* __restrict__ Wr2, const float* __restrict__ Wup,
                           const float* __restrict__ Wcl,
                           unsigned short* __restrict__ o1, unsigned short* __restrict__ o2,
                           unsigned short* __restrict__ o3, unsigned short* __restrict__ o4,
                           unsigned short* __restrict__ o5, unsigned short* __restrict__ o6,
                           unsigned short* __restrict__ o7) {
    int t = blockIdx.x * blockDim.x + threadIdx.x;
    const float* W; unsigned short* O; int Nd, K, idx;
    if (t < 8192)        { W = Wl1; O = o1; Nd = 256;  K = 32;  idx = t; }
    else if (t < 16384)  { W = Wr1; O = o2; Nd = 256;  K = 32;  idx = t - 8192; }
    else if (t < 81920)  { W = Wdn; O = o3; Nd = 256;  K = 256; idx = t - 16384; }
    else if (t < 147456) { W = Wl2; O = o4; Nd = 256;  K = 256; idx = t - 81920; }
    else if (t < 212992) { W = Wr2; O = o5; Nd = 256;  K = 256; idx = t - 147456; }
    else if (t < 278528) { W = Wup; O = o6; Nd = 256;  K = 256; idx = t - 212992; }
    else if (t < 534528) { W = Wcl; O = o7; Nd = 1000; K = 256; idx = t - 278528; }
    else return;
    int n = idx / K, k = idx % K;
    O[idx] = f2b(W[(size_t)k * Nd + n]);
}

// ---- bf16 MFMA GEMM: C[M,N] = A[M,K] @ Bt[N,K]^T (+bias), K multiple of 32
__global__ __launch_bounds__(256) void k_gemm_bf16(
    const unsigned short* __restrict__ A, const unsigned short* __restrict__ Bt,
    float* __restrict__ Cf, unsigned short* __restrict__ Cb,
    const float* __restrict__ bias, int M, int N, int K) {
    __shared__ unsigned short As[8 * 64 * 8];
    __shared__ unsigned short Bs[8 * 64 * 8];
    int tid = threadIdx.x;
    int wave = tid >> 6, lane = tid & 63;
    int wr = wave >> 1, wc = wave & 1;
    int row0 = blockIdx.x * 128, col0 = blockIdx.y * 128;
    floatx4 zero4 = {0.f, 0.f, 0.f, 0.f};
    floatx4 acc[4][4];
#pragma unroll
    for (int i = 0; i < 4; i++)
#pragma unroll
        for (int j = 0; j < 4; j++) acc[i][j] = zero4;
    for (int kb = 0; kb < K; kb += 32) {
#pragma unroll
        for (int q = 0; q < 2; q++) {
            int c = tid * 2 + q;           // 0..511
            int row = c >> 2, koff = (c & 3) * 8;
            int lp = (row & 15) + 16 * (koff >> 3);
            int mt = row >> 4;
            ushort8 va = {0, 0, 0, 0, 0, 0, 0, 0};
            if (row0 + row < M)
                va = *(const ushort8*)(A + (size_t)(row0 + row) * K + kb + koff);
            *(ushort8*)(As + (mt * 64 + lp) * 8) = va;
            ushort8 vb = {0, 0, 0, 0, 0, 0, 0, 0};
            if (col0 + row < N)
                vb = *(const ushort8*)(Bt + (size_t)(col0 + row) * K + kb + koff);
            *(ushort8*)(Bs + (mt * 64 + lp) * 8) = vb;
        }
        __syncthreads();
        bf16x8 af[4], bfr[4];
#pragma unroll
        for (int i = 0; i < 4; i++)
            af[i] = *(const bf16x8*)(As + ((wr * 4 + i) * 64 + lane) * 8);
#pragma unroll
        for (int j = 0; j < 4; j++)
            bfr[j] = *(const bf16x8*)(Bs + ((wc * 4 + j) * 64 + lane) * 8);
#pragma unroll
        for (int i = 0; i < 4; i++)
#pragma unroll
            for (int j = 0; j < 4; j++)
                acc[i][j] = __builtin_amdgcn_mfma_f32_16x16x32_bf16(
                    af[i], bfr[j], acc[i][j], 0, 0, 0);
        __syncthreads();
    }
    int quad = lane >> 4, nl = lane & 15;
#pragma unroll
    for (int i = 0; i < 4; i++) {
#pragma unroll
        for (int j = 0; j < 4; j++) {
            int col = col0 + wc * 64 + j * 16 + nl;
            if (col >= N) continue;
            float bv = bias ? bias[col] : 0.f;
#pragma unroll
            for (int r = 0; r < 4; r++) {
                int rr = row0 + wr * 64 + i * 16 + quad * 4 + r;
                if (rr >= M) continue;
                float v = acc[i][j][r] + bv;
                if (Cf) Cf[(size_t)rr * N + col] = v;
                else Cb[(size_t)rr * N + col] = f2b(v);
            }
        }
    }
}

// ---- CSR build: histogram of dst ----
__global__ void k_hist(const int* __restrict__ dst, int* __restrict__ cnt) {
    int e = blockIdx.x * blockDim.x + threadIdx.x;
    if (e >= N_EDGES) return;
    atomicAdd(cnt + dst[e], 1);
}

// ---- CSR build: fast single-block scan (1024 threads, 20 elems/thread) ----
__global__ __launch_bounds__(1024) void k_scan(const int* __restrict__ cnt,
                                               int* __restrict__ rowptr,
                                               int* __restrict__ wp, int n) {
    __shared__ int tsum[1024];
    int t = threadIdx.x;
    const int chunk = 20;  // 1024*20 = 20480 >= 20000
    int i0 = t * chunk;
    int local[chunk];
    int s = 0;
#pragma unroll
    for (int j = 0; j < chunk; j++) {
        int i = i0 + j;
        int v = (i < n) ? cnt[i] : 0;
        local[j] = s;  // exclusive prefix within chunk
        s += v;
    }
    tsum[t] = s;
    __syncthreads();
    // inclusive Hillis-Steele scan over 1024 partials
    for (int off = 1; off < 1024; off <<= 1) {
        int other = (t >= off) ? tsum[t - off] : 0;
        __syncthreads();
        tsum[t] += other;
        __syncthreads();
    }
    int base = (t > 0) ? tsum[t - 1] : 0;
#pragma unroll
    for (int j = 0; j < chunk; j++) {
        int i = i0 + j;
        if (i < n) {
            int ex = base + local[j];
            rowptr[i] = ex;
            wp[i] = ex;
        }
    }
    if (t == 1023) rowptr[n] = tsum[1023];
}

// ---- CSR build: scatter edge ids into per-dst slots ----
__global__ void k_fill(const int* __restrict__ dst, int* __restrict__ wp,
                       int* __restrict__ eidx) {
    int e = blockIdx.x * blockDim.x + threadIdx.x;
    if (e >= N_EDGES) return;
    int p = atomicAdd(wp + dst[e], 1);
    eidx[p] = e;
}

// ---- fused GATv2 edge phase: wave per dst node, online softmax, no atomics
// depth-3 software pipeline over the dependent chain eidx -> src/ea -> xl-row.
__global__ __launch_bounds__(256) void k_gat_fused(
    const int* __restrict__ rowptr, const int* __restrict__ eidx,
    const int* __restrict__ src, const float* __restrict__ ea,
    const unsigned short* __restrict__ xl, const unsigned short* __restrict__ xr,
    const float* __restrict__ We, const float* __restrict__ att,
    float* __restrict__ out) {
    int node = blockIdx.x * 4 + (threadIdx.x >> 6);
    if (node >= N_NODES) return;
    int lane = threadIdx.x & 63;  // lane covers dims [4*lane, 4*lane+4); head = lane>>3
    int beg = rowptr[node], end = rowptr[node + 1];
    if (beg >= end) {
        ((float4*)(out + (size_t)node * 256))[lane] = make_float4(0.f, 0.f, 0.f, 0.f);
        return;
    }
    float4 wv = ((const float4*)We)[lane];
    float4 av = ((const float4*)att)[lane];
    ushort4 xru = ((const ushort4*)(xr + (size_t)node * 256))[lane];
    float4 rv = make_float4(b2f(xru.x), b2f(xru.y), b2f(xru.z), b2f(xru.w));
    float m = -3.0e38f, l = 0.f;
    float4 acc = make_float4(0.f, 0.f, 0.f, 0.f);
    // pipeline init: x_i,a_i ; s_{i+1},a_{i+1} ; e_{i+2}
    int last = end - 1;
    int eA = eidx[beg];
    int eB = eidx[(beg + 1 < end) ? beg + 1 : last];
    int e2 = eidx[(beg + 2 < end) ? beg + 2 : last];
    int sA = src[eA];        float a0 = ea[eA];
    int s1 = src[eB];        float a1 = ea[eB];
    ushort4 x0 = ((const ushort4*)(xl + (size_t)sA * 256))[lane];
    for (int i = beg; i < end; i++) {
        // issue next-stage loads (each input was fetched a full iteration ago)
        int e3 = eidx[(i + 3 < end) ? i + 3 : last];
        int s2 = src[e2];    float a2 = ea[e2];
        ushort4 x1 = ((const ushort4*)(xl + (size_t)s1 * 256))[lane];
        // compute with (x0, a0)
        float4 lv = make_float4(b2f(x0.x), b2f(x0.y), b2f(x0.z), b2f(x0.w));
        float a = a0;
        float f, p = 0.f;
        f = lv.x + rv.x + a * wv.x; f = (f >= 0.f) ? f : 0.2f * f; p = fmaf(f, av.x, p);
        f = lv.y + rv.y + a * wv.y; f = (f >= 0.f) ? f : 0.2f * f; p = fmaf(f, av.y, p);
        f = lv.z + rv.z + a * wv.z; f = (f >= 0.f) ? f : 0.2f * f; p = fmaf(f, av.z, p);
        f = lv.w + rv.w + a * wv.w; f = (f >= 0.f) ? f : 0.2f * f; p = fmaf(f, av.w, p);
        p += __shfl_xor(p, 1, 64);
        p += __shfl_xor(p, 2, 64);
        p += __shfl_xor(p, 4, 64);
        float mnew = fmaxf(m, p);
        float scale = __expf(m - mnew);
        float w = __expf(p - mnew);
        acc.x = fmaf(acc.x, scale, w * lv.x);
        acc.y = fmaf(acc.y, scale, w * lv.y);
        acc.z = fmaf(acc.z, scale, w * lv.z);
        acc.w = fmaf(acc.w, scale, w * lv.w);
        l = fmaf(l, scale, w);
        m = mnew;
        // shift pipeline
        x0 = x1; a0 = a1; a1 = a2; s1 = s2; e2 = e3;
    }
    float inv = 1.0f / (l + 1e-16f);
    ((float4*)(out + (size_t)node * 256))[lane] =
        make_float4(acc.x * inv, acc.y * inv, acc.z * inv, acc.w * inv);
}

// ---- LayerNorm over 256 dims, one wave per row ----
__global__ void k_ln(const float* __restrict__ in, const float* __restrict__ res,
                     const float* __restrict__ vbias, const float* __restrict__ g,
                     const float* __restrict__ b, float* __restrict__ outf,
                     unsigned short* __restrict__ outb, int rows) {
    int gt = blockIdx.x * blockDim.x + threadIdx.x;
    int wid = gt >> 6, lane = threadIdx.x & 63;
    if (wid >= rows) return;
    float4 v = ((const float4*)(in + (size_t)wid * 256))[lane];
    if (res) {
        float4 r = ((const float4*)(res + (size_t)wid * 256))[lane];
        v.x += r.x; v.y += r.y; v.z += r.z; v.w += r.w;
    }
    if (vbias) {
        float4 r = ((const float4*)vbias)[lane];
        v.x += r.x; v.y += r.y; v.z += r.z; v.w += r.w;
    }
    float sum = v.x + v.y + v.z + v.w;
#pragma unroll
    for (int o = 32; o > 0; o >>= 1) sum += __shfl_xor(sum, o, 64);
    float mean = sum * (1.0f / 256.0f);
    float dx = v.x - mean, dy = v.y - mean, dz = v.z - mean, dw = v.w - mean;
    float sq = dx * dx + dy * dy + dz * dz + dw * dw;
#pragma unroll
    for (int o = 32; o > 0; o >>= 1) sq += __shfl_xor(sq, o, 64);
    float inv = 1.0f / sqrtf(sq * (1.0f / 256.0f) + 1e-5f);
    float4 gg = ((const float4*)g)[lane];
    float4 bb = ((const float4*)b)[lane];
    float4 o4 = make_float4(dx * inv * gg.x + bb.x, dy * inv * gg.y + bb.y,
                            dz * inv * gg.z + bb.z, dw * inv * gg.w + bb.w);
    if (outf) ((float4*)(outf + (size_t)wid * 256))[lane] = o4;
    if (outb) {
        ushort4 u;
        u.x = f2b(o4.x); u.y = f2b(o4.y); u.z = f2b(o4.z); u.w = f2b(o4.w);
        ((ushort4*)(outb + (size_t)wid * 256))[lane] = u;
    }
}

extern "C" void kernel_launch(void* const* d_in, const int* in_sizes, int n_in,
                              void* d_out, int out_size, void* d_ws, size_t ws_size,
                              hipStream_t stream) {
    const float* x_gnn = (const float*)d_in[0];
    const int* ei = (const int*)d_in[1];
    const int* src = ei;
    const int* dst = ei + N_EDGES;
    const float* ea   = (const float*)d_in[2];
    const float* W_in = (const float*)d_in[3];
    const float* b_in = (const float*)d_in[4];
    const float* Wl1  = (const float*)d_in[5];
    const float* Wr1  = (const float*)d_in[6];
    const float* We1  = (const float*)d_in[7];
    const float* att1 = (const float*)d_in[8];
    const float* bg1  = (const float*)d_in[9];
    const float* ln1_g = (const float*)d_in[10];
    const float* ln1_b = (const float*)d_in[11];
    const float* W_down = (const float*)d_in[12];
    const float* lnd_g = (const float*)d_in[13];
    const float* lnd_b = (const float*)d_in[14];
    const float* Wl2  = (const float*)d_in[15];
    const float* Wr2  = (const float*)d_in[16];
    const float* We2  = (const float*)d_in[17];
    const float* att2 = (const float*)d_in[18];
    const float* bg2  = (const float*)d_in[19];
    const float* ln2_g = (const float*)d_in[20];
    const float* ln2_b = (const float*)d_in[21];
    const float* W_up = (const float*)d_in[22];
    const float* lnu_g = (const float*)d_in[23];
    const float* lnu_b = (const float*)d_in[24];
    const float* W_cls = (const float*)d_in[25];
    const float* b_cls = (const float*)d_in[26];

    // ---- workspace layout ----
    float* ws = (float*)d_ws;
    float* B_agg = ws;                                // 5,120,000 f
    float* B_h1  = B_agg + 5120000;                   // 5,120,000 f
    float* B_z   = B_h1 + 5120000;                    // 5,120,000 f
    unsigned short* B_xl = (unsigned short*)(B_z + 5120000);   // 5,120,000 us
    unsigned short* B_xr = B_xl + 5120000;                     // 5,120,000 us
    unsigned short* B_actb = B_xr + 5120000;                   // 5,120,000 us
    unsigned short* B_h0b = B_actb + 5120000;                  // 640,000 us
    unsigned short* Wt_l1 = B_h0b + 640000;                    // 8,192
    unsigned short* Wt_r1 = Wt_l1 + 8192;                      // 8,192
    unsigned short* Wt_down = Wt_r1 + 8192;                    // 65,536
    unsigned short* Wt_l2 = Wt_down + 65536;
    unsigned short* Wt_r2 = Wt_l2 + 65536;
    unsigned short* Wt_up = Wt_r2 + 65536;
    unsigned short* Wt_cls = Wt_up + 65536;                    // 256,000
    int* C_cnt = (int*)(Wt_cls + 256000 + (256000 & 1));       // 20,000
    int* C_row = C_cnt + 20000;                                // 20,001
    int* C_wp  = C_row + 20001;                                // 20,000
    int* C_eid = C_wp + 20000;                                 // 320,000

    float* out_logits = (float*)d_out;
    float* out_h = out_logits + (size_t)N_NODES * 1000;

    int lnblk = (N_NODES * 64 + 255) / 256;
    int gatblk = (N_NODES + 3) / 4;
    dim3 gg((N_NODES + 127) / 128, 2);   // N=256
    dim3 gc((N_NODES + 127) / 128, 8);   // N=1000

    // 0. build CSR over dst (reused by both GAT layers)
    hipMemsetAsync(C_cnt, 0, (size_t)20000 * 4, stream);
    k_hist<<<(N_EDGES + 255) / 256, 256, 0, stream>>>(dst, C_cnt);
    k_scan<<<1, 1024, 0, stream>>>(C_cnt, C_row, C_wp, N_NODES);
    k_fill<<<(N_EDGES + 255) / 256, 256, 0, stream>>>(dst, C_wp, C_eid);

    // 0b. all weight converts in one launch
    k_wcvt_all<<<(534528 + 255) / 256, 256, 0, stream>>>(
        Wl1, Wr1, W_down, Wl2, Wr2, W_up, W_cls,
        Wt_l1, Wt_r1, Wt_down, Wt_l2, Wt_r2, Wt_up, Wt_cls);

    // 1. h0 = x @ W_in + b_in (bf16)
    k_inproj<<<(N_NODES * 32 + 255) / 256, 256, 0, stream>>>(x_gnn, W_in, b_in, B_h0b);
    // 2. xl1 = h0@Wl1, xr1 = h0@Wr1 (K=32 MFMA, bf16 out)
    k_gemm_bf16<<<gg, 256, 0, stream>>>(B_h0b, Wt_l1, nullptr, B_xl, nullptr, N_NODES, 256, 32);
    k_gemm_bf16<<<gg, 256, 0, stream>>>(B_h0b, Wt_r1, nullptr, B_xr, nullptr, N_NODES, 256, 32);
    // 3. GAT1 fused -> B_agg
    k_gat_fused<<<gatblk, 256, 0, stream>>>(C_row, C_eid, src, ea, B_xl, B_xr, We1, att1, B_agg);
    // 4. h1 = LN(agg1 + bg1) (fp32 + bf16)
    k_ln<<<lnblk, 256, 0, stream>>>(B_agg, nullptr, bg1, ln1_g, ln1_b, B_h1, B_actb, N_NODES);
    // 5. z = LN(h1 @ W_down)
    k_gemm_bf16<<<gg, 256, 0, stream>>>(B_actb, Wt_down, B_agg, nullptr, nullptr, N_NODES, 256, 256);
    k_ln<<<lnblk, 256, 0, stream>>>(B_agg, nullptr, nullptr, lnd_g, lnd_b, B_z, B_actb, N_NODES);
    // 6. xl2/xr2 (bf16 out) + GAT2 fused
    k_gemm_bf16<<<gg, 256, 0, stream>>>(B_actb, Wt_l2, nullptr, B_xl, nullptr, N_NODES, 256, 256);
    k_gemm_bf16<<<gg, 256, 0, stream>>>(B_actb, Wt_r2, nullptr, B_xr, nullptr, N_NODES, 256, 256);
    k_gat_fused<<<gatblk, 256, 0, stream>>>(C_row, C_eid, src, ea, B_xl, B_xr, We2, att2, B_agg);
    // 7. z2 = LN(agg2 + bg2 + z) -> bf16 only
    k_ln<<<lnblk, 256, 0, stream>>>(B_agg, B_z, bg2, ln2_g, ln2_b, nullptr, B_actb, N_NODES);
    // 8. h2 = z2 @ W_up -> B_agg
    k_gemm_bf16<<<gg, 256, 0, stream>>>(B_actb, Wt_up, B_agg, nullptr, nullptr, N_NODES, 256, 256);
    // 9. h = LN(h2 + h1) -> out_h (fp32) + bf16
    k_ln<<<lnblk, 256, 0, stream>>>(B_agg, B_h1, nullptr, lnu_g, lnu_b, out_h, B_actb, N_NODES);
    // 10. logits = h @ W_cls + b_cls
    k_gemm_bf16<<<gc, 256, 0, stream>>>(B_actb, Wt_cls, out_logits, nullptr, b_cls, N_NODES, 1000, 256);
}